// Round 5
// baseline (1427.846 us; speedup 1.0000x reference)
//
#include <hip/hip_runtime.h>
#include <math.h>

#define NN 20000
#define NE 320000
#define TS 16
#define HG 64
#define HTT 128
#define NG 384   // 3*HT
#define LN_EPS 1e-5f

typedef __attribute__((ext_vector_type(8))) short bf16x8;
typedef __attribute__((ext_vector_type(4))) float f32x4;

__device__ __forceinline__ float wave_sum64(float v) {
  #pragma unroll
  for (int off = 32; off > 0; off >>= 1) v += __shfl_xor(v, off, 64);
  return v;
}
__device__ __forceinline__ float quad_sum16(float v) {
  #pragma unroll
  for (int off = 1; off < 16; off <<= 1) v += __shfl_xor(v, off, 64);
  return v;
}

__device__ __forceinline__ unsigned short f2bf(float x) {
  unsigned u = __float_as_uint(x);
  unsigned r = u + 0x7FFFu + ((u >> 16) & 1u);   // RNE to bf16
  return (unsigned short)(r >> 16);
}
__device__ __forceinline__ float bf2f(unsigned short h) {
  return __uint_as_float(((unsigned)h) << 16);
}

// ---------------- setup ----------------
__global__ void k_init(int* cnt, float* h, unsigned short* h_hi, unsigned short* h_lo) {
  int i = blockIdx.x * blockDim.x + threadIdx.x;
  int stride = gridDim.x * blockDim.x;
  for (int j = i; j < NN; j += stride) cnt[j] = 0;
  for (int j = i; j < NN * HTT; j += stride) {
    h[j] = 0.f; h_hi[j] = 0; h_lo[j] = 0;
  }
}

__global__ void k_hist(const int* __restrict__ dst, int* cnt) {
  int e = blockIdx.x * blockDim.x + threadIdx.x;
  if (e < NE) atomicAdd(&cnt[dst[e]], 1);
}

__global__ void k_scan(int* cnt, int* row_ptr, float* deg_inv) {
  __shared__ int s[1024];
  int tid = threadIdx.x;
  int carry = 0;
  for (int base = 0; base < NN; base += 1024) {
    int n = base + tid;
    int v = (n < NN) ? cnt[n] : 0;
    s[tid] = v;
    __syncthreads();
    for (int off = 1; off < 1024; off <<= 1) {
      int t = (tid >= off) ? s[tid - off] : 0;
      __syncthreads();
      s[tid] += t;
      __syncthreads();
    }
    int incl = s[tid];
    if (n < NN) {
      int excl = carry + incl - v;
      row_ptr[n] = excl;
      cnt[n] = excl;
      deg_inv[n] = 1.0f / (float)((v > 1) ? v : 1);
    }
    carry += s[1023];
    __syncthreads();
  }
  if (tid == 0) row_ptr[NN] = carry;
}

__global__ void k_fill(const int* __restrict__ src, const int* __restrict__ dst,
                       int* cursor, int* col) {
  int e = blockIdx.x * blockDim.x + threadIdx.x;
  if (e < NE) {
    int p = atomicAdd(&cursor[dst[e]], 1);
    col[p] = src[e];
  }
}

__global__ void k_cvt(const float* __restrict__ w, unsigned short* __restrict__ hi,
                      unsigned short* __restrict__ lo, int n) {
  int i = blockIdx.x * blockDim.x + threadIdx.x;
  if (i < n) {
    float x = w[i];
    unsigned short h = f2bf(x);
    hi[i] = h;
    lo[i] = f2bf(x - bf2f(h));
  }
}

// combined sage weight, transposed: Wc[n][k], k<64 -> Wl1[k][n], else Wr1[k-64][n]
__global__ void k_cvt_sage(const float* __restrict__ Wl1, const float* __restrict__ Wr1,
                           unsigned short* __restrict__ hi, unsigned short* __restrict__ lo) {
  int i = blockIdx.x * blockDim.x + threadIdx.x;   // i = n*128 + k
  if (i < HG * 128) {
    int n = i >> 7, k = i & 127;
    float x = (k < HG) ? Wl1[k * HG + n] : Wr1[(k - HG) * HG + n];
    unsigned short h = f2bf(x);
    hi[i] = h;
    lo[i] = f2bf(x - bf2f(h));
  }
}

// ---------------- SAGE layer 0 (F=1 -> HG): fp32 + split planes ----------------
__global__ __launch_bounds__(256) void k_sage0(
    const float* __restrict__ x_t,
    const int* __restrict__ row_ptr, const int* __restrict__ col,
    const float* __restrict__ deg_inv,
    const float* __restrict__ Wl0, const float* __restrict__ Wr0,
    const float* __restrict__ b0,
    const float* __restrict__ g0, const float* __restrict__ be0,
    float* __restrict__ h0f, unsigned short* __restrict__ h0hi, unsigned short* __restrict__ h0lo) {
  int lane = threadIdx.x & 63;
  int n = blockIdx.x * 4 + (threadIdx.x >> 6);
  if (n >= NN) return;
  int beg = row_ptr[n], end = row_ptr[n + 1];
  float s = 0.f;
  for (int e = beg + lane; e < end; e += 64) s += x_t[col[e]];
  float a = wave_sum64(s) * deg_inv[n];
  float xn = x_t[n];
  float v = a * Wl0[lane] + xn * Wr0[lane] + b0[lane];
  float mu = wave_sum64(v) * (1.f / 64.f);
  float d = v - mu;
  float var = wave_sum64(d * d) * (1.f / 64.f);
  float o = d * rsqrtf(var + LN_EPS) * g0[lane] + be0[lane];
  o = fmaxf(o, 0.f);
  h0f[n * HG + lane] = o;
  unsigned short hh = f2bf(o);
  h0hi[n * HG + lane] = hh;
  h0lo[n * HG + lane] = f2bf(o - bf2f(hh));
}

// ---------------- fused per-step kernel: gather + SAGE-MM + GRU ----------------
// block = 256 threads = 4 waves, 32 nodes/block (grid 625*32 = 20000 exactly).
// Phase A: wave w gathers nodes [w*8, w*8+8) -> aggL (fp32, LDS).
// Phase B: waves 0,1 each do one 16-node m-tile of C=[agg|h0]@Wc^T (split-bf16
//          MFMA, K=128) + bias + LN + ReLU -> HtL (split-bf16, LDS).
// Phase C: all 4 waves: GRU. wave w owns gate cols j in [32w, 32w+32):
//          acc[0,1]=r acc[2,3]=z acc[4,5]=Ni acc[6,7]=Nh ; 2nd idx = m-tile.
__global__ __launch_bounds__(256, 3) void k_step(
    const float* __restrict__ h0f,
    const unsigned short* __restrict__ h0hi, const unsigned short* __restrict__ h0lo,
    const int* __restrict__ row_ptr, const int* __restrict__ col,
    const float* __restrict__ deg_inv,
    const unsigned short* __restrict__ Wchi, const unsigned short* __restrict__ Wclo, // 64 x 128
    const float* __restrict__ b1, const float* __restrict__ g1, const float* __restrict__ be1,
    const unsigned short* __restrict__ Wih_hi, const unsigned short* __restrict__ Wih_lo, // 384 x 64
    const unsigned short* __restrict__ Whh_hi, const unsigned short* __restrict__ Whh_lo, // 384 x 128
    const unsigned short* __restrict__ Hhi, const unsigned short* __restrict__ Hlo,   // h planes (NN x 128)
    const float* __restrict__ bih, const float* __restrict__ bhh,
    float* __restrict__ h, unsigned short* __restrict__ h_hi, unsigned short* __restrict__ h_lo) {
  __shared__ float aggL[32][68];            // padded: stride 68 fp32 (272B, 16B aligned)
  __shared__ unsigned short HtHiL[32][80];  // padded: stride 80 ushort (160B, 16B aligned)
  __shared__ unsigned short HtLoL[32][80];

  int tid = threadIdx.x;
  int lane = tid & 63, wave = tid >> 6;
  int col16 = lane & 15, quad = lane >> 4;
  int m0 = blockIdx.x * 32;

  // ---------- Phase A: gather 8 nodes per wave ----------
  for (int i = 0; i < 8; i++) {
    int nl = wave * 8 + i;                  // local node
    int n = m0 + nl;
    int beg = row_ptr[n], end = row_ptr[n + 1];
    int deg = end - beg;
    float a0 = 0.f, a1 = 0.f, a2 = 0.f, a3 = 0.f,
          a4 = 0.f, a5 = 0.f, a6 = 0.f, a7 = 0.f;
    for (int base = 0; base < deg; base += 64) {
      int lim = deg - base; if (lim > 64) lim = 64;
      int c = (base + lane < deg) ? col[beg + base + lane] : 0;
      int k = 0;
      for (; k + 8 <= lim; k += 8) {
        int c0 = __shfl(c, k + 0), c1 = __shfl(c, k + 1);
        int c2 = __shfl(c, k + 2), c3 = __shfl(c, k + 3);
        int c4 = __shfl(c, k + 4), c5 = __shfl(c, k + 5);
        int c6 = __shfl(c, k + 6), c7 = __shfl(c, k + 7);
        a0 += h0f[c0 * HG + lane]; a1 += h0f[c1 * HG + lane];
        a2 += h0f[c2 * HG + lane]; a3 += h0f[c3 * HG + lane];
        a4 += h0f[c4 * HG + lane]; a5 += h0f[c5 * HG + lane];
        a6 += h0f[c6 * HG + lane]; a7 += h0f[c7 * HG + lane];
      }
      for (; k < lim; k++) a0 += h0f[__shfl(c, k) * HG + lane];
    }
    float aggv = (((a0 + a1) + (a2 + a3)) + ((a4 + a5) + (a6 + a7))) * deg_inv[n];
    aggL[nl][lane] = aggv;
  }
  __syncthreads();

  // ---------- Phase B: SAGE GEMM + LN + ReLU (waves 0,1) ----------
  if (wave < 2) {
    int mloc = wave * 16 + col16;           // local node for A-fragments
    int arow = m0 + mloc;                   // global node
    f32x4 acc[4];
    #pragma unroll
    for (int nt = 0; nt < 4; nt++) acc[nt] = (f32x4){0.f, 0.f, 0.f, 0.f};

    // K = 0..63 : agg (from LDS, split on the fly)
    #pragma unroll
    for (int kk = 0; kk < HG; kk += 32) {
      float af[8];
      #pragma unroll
      for (int j = 0; j < 8; j++) af[j] = aggL[mloc][kk + quad * 8 + j];
      bf16x8 ah, al;
      #pragma unroll
      for (int j = 0; j < 8; j++) {
        unsigned short hh = f2bf(af[j]);
        ah[j] = (short)hh;
        al[j] = (short)f2bf(af[j] - bf2f(hh));
      }
      #pragma unroll
      for (int nt = 0; nt < 4; nt++) {
        int n = nt * 16 + col16;
        bf16x8 bh = *(const bf16x8*)&Wchi[n * 128 + kk + quad * 8];
        bf16x8 bl = *(const bf16x8*)&Wclo[n * 128 + kk + quad * 8];
        acc[nt] = __builtin_amdgcn_mfma_f32_16x16x32_bf16(ah, bh, acc[nt], 0, 0, 0);
        acc[nt] = __builtin_amdgcn_mfma_f32_16x16x32_bf16(al, bh, acc[nt], 0, 0, 0);
        acc[nt] = __builtin_amdgcn_mfma_f32_16x16x32_bf16(ah, bl, acc[nt], 0, 0, 0);
      }
    }
    // K = 64..127 : h0 (global planes)
    #pragma unroll
    for (int kk = 0; kk < HG; kk += 32) {
      bf16x8 ah = *(const bf16x8*)&h0hi[arow * HG + kk + quad * 8];
      bf16x8 al = *(const bf16x8*)&h0lo[arow * HG + kk + quad * 8];
      #pragma unroll
      for (int nt = 0; nt < 4; nt++) {
        int n = nt * 16 + col16;
        bf16x8 bh = *(const bf16x8*)&Wchi[n * 128 + 64 + kk + quad * 8];
        bf16x8 bl = *(const bf16x8*)&Wclo[n * 128 + 64 + kk + quad * 8];
        acc[nt] = __builtin_amdgcn_mfma_f32_16x16x32_bf16(ah, bh, acc[nt], 0, 0, 0);
        acc[nt] = __builtin_amdgcn_mfma_f32_16x16x32_bf16(al, bh, acc[nt], 0, 0, 0);
        acc[nt] = __builtin_amdgcn_mfma_f32_16x16x32_bf16(ah, bl, acc[nt], 0, 0, 0);
      }
    }

    // bias + LN + ReLU. lane holds node (wave*16 + quad*4 + r), feat nt*16+col16.
    float bias[4], gg[4], bb[4];
    #pragma unroll
    for (int nt = 0; nt < 4; nt++) {
      int n = nt * 16 + col16;
      bias[nt] = b1[n]; gg[nt] = g1[n]; bb[nt] = be1[n];
    }
    #pragma unroll
    for (int r = 0; r < 4; r++) {
      float v[4];
      #pragma unroll
      for (int nt = 0; nt < 4; nt++) v[nt] = acc[nt][r] + bias[nt];
      float s = (v[0] + v[1]) + (v[2] + v[3]);
      float mu = quad_sum16(s) * (1.f / 64.f);
      float sq = 0.f;
      #pragma unroll
      for (int nt = 0; nt < 4; nt++) { v[nt] -= mu; sq += v[nt] * v[nt]; }
      float var = quad_sum16(sq) * (1.f / 64.f);
      float rstd = rsqrtf(var + LN_EPS);
      int ml = wave * 16 + quad * 4 + r;
      #pragma unroll
      for (int nt = 0; nt < 4; nt++) {
        float o = fmaxf(v[nt] * rstd * gg[nt] + bb[nt], 0.f);
        unsigned short hh = f2bf(o);
        HtHiL[ml][nt * 16 + col16] = hh;
        HtLoL[ml][nt * 16 + col16] = f2bf(o - bf2f(hh));
      }
    }
  }
  __syncthreads();

  // ---------- Phase C: GRU ----------
  int gb = 2 * wave;
  f32x4 acc[8][2];
  #pragma unroll
  for (int a = 0; a < 8; a++)
    #pragma unroll
    for (int mt = 0; mt < 2; mt++) acc[a][mt] = (f32x4){0.f, 0.f, 0.f, 0.f};

  // gi: A = Ht (LDS, K=64), W = Wih
  #pragma unroll
  for (int kk = 0; kk < HG; kk += 32) {
    bf16x8 ah[2], al[2];
    #pragma unroll
    for (int mt = 0; mt < 2; mt++) {
      int ml = mt * 16 + col16;
      ah[mt] = *(const bf16x8*)&HtHiL[ml][kk + quad * 8];
      al[mt] = *(const bf16x8*)&HtLoL[ml][kk + quad * 8];
    }
    #pragma unroll
    for (int t6 = 0; t6 < 6; t6++) {
      int gt = (t6 < 2) ? (gb + t6) : (t6 < 4) ? (8 + gb + t6 - 2) : (16 + gb + t6 - 4);
      size_t o = (size_t)(gt * 16 + col16) * HG + kk + quad * 8;
      bf16x8 bh = *(const bf16x8*)&Wih_hi[o];
      bf16x8 bl = *(const bf16x8*)&Wih_lo[o];
      #pragma unroll
      for (int mt = 0; mt < 2; mt++) {
        acc[t6][mt] = __builtin_amdgcn_mfma_f32_16x16x32_bf16(ah[mt], bh, acc[t6][mt], 0, 0, 0);
        acc[t6][mt] = __builtin_amdgcn_mfma_f32_16x16x32_bf16(al[mt], bh, acc[t6][mt], 0, 0, 0);
        acc[t6][mt] = __builtin_amdgcn_mfma_f32_16x16x32_bf16(ah[mt], bl, acc[t6][mt], 0, 0, 0);
      }
    }
  }
  // gh: A = h (global planes, K=128), W = Whh
  #pragma unroll
  for (int kk = 0; kk < HTT; kk += 32) {
    bf16x8 ah[2], al[2];
    #pragma unroll
    for (int mt = 0; mt < 2; mt++) {
      size_t o = (size_t)(m0 + mt * 16 + col16) * HTT + kk + quad * 8;
      ah[mt] = *(const bf16x8*)&Hhi[o];
      al[mt] = *(const bf16x8*)&Hlo[o];
    }
    #pragma unroll
    for (int t6 = 0; t6 < 6; t6++) {
      int gt = (t6 < 2) ? (gb + t6) : (t6 < 4) ? (8 + gb + t6 - 2) : (16 + gb + t6 - 4);
      int ai = (t6 < 4) ? t6 : t6 + 2;
      size_t o = (size_t)(gt * 16 + col16) * HTT + kk + quad * 8;
      bf16x8 bh = *(const bf16x8*)&Whh_hi[o];
      bf16x8 bl = *(const bf16x8*)&Whh_lo[o];
      #pragma unroll
      for (int mt = 0; mt < 2; mt++) {
        acc[ai][mt] = __builtin_amdgcn_mfma_f32_16x16x32_bf16(ah[mt], bh, acc[ai][mt], 0, 0, 0);
        acc[ai][mt] = __builtin_amdgcn_mfma_f32_16x16x32_bf16(al[mt], bh, acc[ai][mt], 0, 0, 0);
        acc[ai][mt] = __builtin_amdgcn_mfma_f32_16x16x32_bf16(ah[mt], bl, acc[ai][mt], 0, 0, 0);
      }
    }
  }

  // gates in registers: lane holds (m = m0+mt*16+quad*4+r, j = (gb+js)*16+col16)
  int jj[2]; float bR[2], bZ[2], bNi[2], bNh[2];
  #pragma unroll
  for (int js = 0; js < 2; js++) {
    int j = (gb + js) * 16 + col16;
    jj[js] = j;
    bR[js]  = bih[j] + bhh[j];
    bZ[js]  = bih[HTT + j] + bhh[HTT + j];
    bNi[js] = bih[2 * HTT + j];
    bNh[js] = bhh[2 * HTT + j];
  }
  #pragma unroll
  for (int mt = 0; mt < 2; mt++) {
    #pragma unroll
    for (int r = 0; r < 4; r++) {
      int m = m0 + mt * 16 + quad * 4 + r;
      #pragma unroll
      for (int js = 0; js < 2; js++) {
        int j = jj[js];
        float R  = acc[0 + js][mt][r] + bR[js];
        float Z  = acc[2 + js][mt][r] + bZ[js];
        float Ni = acc[4 + js][mt][r] + bNi[js];
        float Nh = acc[6 + js][mt][r] + bNh[js];
        float rg = 1.f / (1.f + __expf(-R));
        float zg = 1.f / (1.f + __expf(-Z));
        float x = Ni + rg * Nh;
        float e = __expf(-2.f * fabsf(x));
        float th = (1.f - e) / (1.f + e);
        float nn = copysignf(th, x);
        size_t idx = (size_t)m * HTT + j;
        float hn = (1.f - zg) * nn + zg * h[idx];
        h[idx] = hn;
        unsigned short hh = f2bf(hn);
        h_hi[idx] = hh;
        h_lo[idx] = f2bf(hn - bf2f(hh));
      }
    }
  }
}

// ---------------- head ----------------
__global__ __launch_bounds__(256) void k_head(
    const float* __restrict__ h, const float* __restrict__ hw,
    const float* __restrict__ hb, float* __restrict__ out) {
  int lane = threadIdx.x & 63;
  int n = blockIdx.x * 4 + (threadIdx.x >> 6);
  if (n >= NN) return;
  float v = h[n * HTT + lane] * hw[lane] + h[n * HTT + 64 + lane] * hw[64 + lane];
  v = wave_sum64(v);
  if (lane == 0) out[n] = v + hb[0];
}

extern "C" void kernel_launch(void* const* d_in, const int* in_sizes, int n_in,
                              void* d_out, int out_size, void* d_ws, size_t ws_size,
                              hipStream_t stream) {
  const float* x_seq = (const float*)d_in[0];
  const int*   edge  = (const int*)d_in[1];
  const float* Wl0   = (const float*)d_in[2];
  const float* Wr0   = (const float*)d_in[3];
  const float* b0    = (const float*)d_in[4];
  const float* g0    = (const float*)d_in[5];
  const float* be0   = (const float*)d_in[6];
  const float* Wl1   = (const float*)d_in[7];
  const float* Wr1   = (const float*)d_in[8];
  const float* b1    = (const float*)d_in[9];
  const float* g1    = (const float*)d_in[10];
  const float* be1   = (const float*)d_in[11];
  const float* Wih   = (const float*)d_in[12];
  const float* Whh   = (const float*)d_in[13];
  const float* bih   = (const float*)d_in[14];
  const float* bhh   = (const float*)d_in[15];
  const float* headW = (const float*)d_in[16];
  const float* headb = (const float*)d_in[17];
  float* out = (float*)d_out;

  const int* srcp = edge;
  const int* dstp = edge + NE;

  char* ws = (char*)d_ws;
  size_t off = 0;
  auto alloc = [&](size_t bytes) -> void* {
    void* p = ws + off;
    off += (bytes + 255) & ~(size_t)255;
    return p;
  };
  int*   cnt     = (int*)alloc(NN * 4);
  int*   row_ptr = (int*)alloc((NN + 1) * 4);
  int*   col     = (int*)alloc(NE * 4);
  float* deg_inv = (float*)alloc(NN * 4);
  float* h0f     = (float*)alloc((size_t)NN * HG * 4);
  unsigned short* h0hi  = (unsigned short*)alloc((size_t)NN * HG * 2);
  unsigned short* h0lo  = (unsigned short*)alloc((size_t)NN * HG * 2);
  float* h       = (float*)alloc((size_t)NN * HTT * 4);
  unsigned short* h_hi = (unsigned short*)alloc((size_t)NN * HTT * 2);
  unsigned short* h_lo = (unsigned short*)alloc((size_t)NN * HTT * 2);
  unsigned short* Wih_hi = (unsigned short*)alloc((size_t)NG * HG * 2);
  unsigned short* Wih_lo = (unsigned short*)alloc((size_t)NG * HG * 2);
  unsigned short* Whh_hi = (unsigned short*)alloc((size_t)NG * HTT * 2);
  unsigned short* Whh_lo = (unsigned short*)alloc((size_t)NG * HTT * 2);
  unsigned short* Wchi   = (unsigned short*)alloc((size_t)HG * 128 * 2);
  unsigned short* Wclo   = (unsigned short*)alloc((size_t)HG * 128 * 2);
  (void)ws_size; (void)in_sizes; (void)n_in; (void)out_size;

  k_init<<<512, 256, 0, stream>>>(cnt, h, h_hi, h_lo);
  k_hist<<<(NE + 255) / 256, 256, 0, stream>>>(dstp, cnt);
  k_scan<<<1, 1024, 0, stream>>>(cnt, row_ptr, deg_inv);
  k_fill<<<(NE + 255) / 256, 256, 0, stream>>>(srcp, dstp, cnt, col);
  k_cvt<<<(NG * HG + 255) / 256, 256, 0, stream>>>(Wih, Wih_hi, Wih_lo, NG * HG);
  k_cvt<<<(NG * HTT + 255) / 256, 256, 0, stream>>>(Whh, Whh_hi, Whh_lo, NG * HTT);
  k_cvt_sage<<<(HG * 128 + 255) / 256, 256, 0, stream>>>(Wl1, Wr1, Wchi, Wclo);

  for (int t = 0; t < TS; t++) {
    const float* x_t = x_seq + (size_t)t * NN;
    k_sage0<<<5000, 256, 0, stream>>>(x_t, row_ptr, col, deg_inv,
                                      Wl0, Wr0, b0, g0, be0, h0f, h0hi, h0lo);
    k_step<<<NN / 32, 256, 0, stream>>>(h0f, h0hi, h0lo, row_ptr, col, deg_inv,
                                        Wchi, Wclo, b1, g1, be1,
                                        Wih_hi, Wih_lo, Whh_hi, Whh_lo,
                                        h_hi, h_lo, bih, bhh,
                                        h, h_hi, h_lo);
  }
  k_head<<<5000, 256, 0, stream>>>(h, headW, headb, out);
}

// Round 6
// 678.469 us; speedup vs baseline: 2.1045x; 2.1045x over previous
//
#include <hip/hip_runtime.h>
#include <math.h>

#define NN 20000
#define NE 320000
#define TS 16
#define HG 64
#define HTT 128
#define NG 384   // 3*HT
#define LN_EPS 1e-5f

typedef __attribute__((ext_vector_type(8))) short bf16x8;
typedef __attribute__((ext_vector_type(8))) _Float16 f16x8;
typedef __attribute__((ext_vector_type(4))) float f32x4;

__device__ __forceinline__ float wave_sum64(float v) {
  #pragma unroll
  for (int off = 32; off > 0; off >>= 1) v += __shfl_xor(v, off, 64);
  return v;
}
__device__ __forceinline__ float quad_sum16(float v) {
  #pragma unroll
  for (int off = 1; off < 16; off <<= 1) v += __shfl_xor(v, off, 64);
  return v;
}

__device__ __forceinline__ unsigned short f2bf(float x) {
  unsigned u = __float_as_uint(x);
  unsigned r = u + 0x7FFFu + ((u >> 16) & 1u);   // RNE to bf16
  return (unsigned short)(r >> 16);
}
__device__ __forceinline__ float bf2f(unsigned short h) {
  return __uint_as_float(((unsigned)h) << 16);
}

// ---------------- setup ----------------
__global__ void k_init(int* cnt) {
  int i = blockIdx.x * blockDim.x + threadIdx.x;
  if (i < NN) cnt[i] = 0;
}

__global__ void k_hist(const int* __restrict__ dst, int* cnt) {
  int e = blockIdx.x * blockDim.x + threadIdx.x;
  if (e < NE) atomicAdd(&cnt[dst[e]], 1);
}

__global__ void k_scan(int* cnt, int* row_ptr, float* deg_inv) {
  __shared__ int s[1024];
  int tid = threadIdx.x;
  int carry = 0;
  for (int base = 0; base < NN; base += 1024) {
    int n = base + tid;
    int v = (n < NN) ? cnt[n] : 0;
    s[tid] = v;
    __syncthreads();
    for (int off = 1; off < 1024; off <<= 1) {
      int t = (tid >= off) ? s[tid - off] : 0;
      __syncthreads();
      s[tid] += t;
      __syncthreads();
    }
    int incl = s[tid];
    if (n < NN) {
      int excl = carry + incl - v;
      row_ptr[n] = excl;
      cnt[n] = excl;
      deg_inv[n] = 1.0f / (float)((v > 1) ? v : 1);
    }
    carry += s[1023];
    __syncthreads();
  }
  if (tid == 0) row_ptr[NN] = carry;
}

__global__ void k_fill(const int* __restrict__ src, const int* __restrict__ dst,
                       int* cursor, int* col) {
  int e = blockIdx.x * blockDim.x + threadIdx.x;
  if (e < NE) {
    int p = atomicAdd(&cursor[dst[e]], 1);
    col[p] = src[e];
  }
}

__global__ void k_cvt_f16(const float* __restrict__ w, _Float16* __restrict__ o, int n) {
  int i = blockIdx.x * blockDim.x + threadIdx.x;
  if (i < n) o[i] = (_Float16)w[i];
}

// combined sage weight, transposed, split-bf16: Wc[n][k], k<64 -> Wl1[k][n], else Wr1
__global__ void k_cvt_sage(const float* __restrict__ Wl1, const float* __restrict__ Wr1,
                           unsigned short* __restrict__ hi, unsigned short* __restrict__ lo) {
  int i = blockIdx.x * blockDim.x + threadIdx.x;   // i = n*128 + k
  if (i < HG * 128) {
    int n = i >> 7, k = i & 127;
    float x = (k < HG) ? Wl1[k * HG + n] : Wr1[(k - HG) * HG + n];
    unsigned short h = f2bf(x);
    hi[i] = h;
    lo[i] = f2bf(x - bf2f(h));
  }
}

// ---------------- SAGE layer 0, ALL timesteps in parallel ----------------
__global__ __launch_bounds__(256) void k_sage0_all(
    const float* __restrict__ x_seq,
    const int* __restrict__ row_ptr, const int* __restrict__ col,
    const float* __restrict__ deg_inv,
    const float* __restrict__ Wl0, const float* __restrict__ Wr0,
    const float* __restrict__ b0,
    const float* __restrict__ g0, const float* __restrict__ be0,
    float* __restrict__ h0f_all) {
  int t = blockIdx.y;
  const float* x_t = x_seq + (size_t)t * NN;
  int lane = threadIdx.x & 63;
  int n = blockIdx.x * 4 + (threadIdx.x >> 6);
  if (n >= NN) return;
  int beg = row_ptr[n], end = row_ptr[n + 1];
  float s = 0.f;
  for (int e = beg + lane; e < end; e += 64) s += x_t[col[e]];
  float a = wave_sum64(s) * deg_inv[n];
  float xn = x_t[n];
  float v = a * Wl0[lane] + xn * Wr0[lane] + b0[lane];
  float mu = wave_sum64(v) * (1.f / 64.f);
  float d = v - mu;
  float var = wave_sum64(d * d) * (1.f / 64.f);
  float o = d * rsqrtf(var + LN_EPS) * g0[lane] + be0[lane];
  h0f_all[((size_t)t * NN + n) * HG + lane] = fmaxf(o, 0.f);
}

// ---------------- SAGE layer 1 (gather + MFMA GEMM + LN), ALL t parallel ----------------
// grid (625, 16); 32 nodes per block. Output: Ht split-fp16 planes.
__global__ __launch_bounds__(256) void k_sage_all(
    const float* __restrict__ h0f_all,
    const int* __restrict__ row_ptr, const int* __restrict__ col,
    const float* __restrict__ deg_inv,
    const unsigned short* __restrict__ Wchi, const unsigned short* __restrict__ Wclo, // 64 x 128
    const float* __restrict__ b1, const float* __restrict__ g1, const float* __restrict__ be1,
    _Float16* __restrict__ HtHi_all, _Float16* __restrict__ HtLo_all) {
  __shared__ float aggL[32][68];
  int t = blockIdx.y;
  const float* h0f = h0f_all + (size_t)t * NN * HG;
  int tid = threadIdx.x;
  int lane = tid & 63, wave = tid >> 6;
  int col16 = lane & 15, quad = lane >> 4;
  int m0 = blockIdx.x * 32;

  // Phase A: each wave gathers 8 nodes (8-way ILP)
  for (int i = 0; i < 8; i++) {
    int nl = wave * 8 + i;
    int n = m0 + nl;
    int beg = row_ptr[n], end = row_ptr[n + 1];
    int deg = end - beg;
    float a0 = 0.f, a1 = 0.f, a2 = 0.f, a3 = 0.f,
          a4 = 0.f, a5 = 0.f, a6 = 0.f, a7 = 0.f;
    for (int base = 0; base < deg; base += 64) {
      int lim = deg - base; if (lim > 64) lim = 64;
      int c = (base + lane < deg) ? col[beg + base + lane] : 0;
      int k = 0;
      for (; k + 8 <= lim; k += 8) {
        int c0 = __shfl(c, k + 0), c1 = __shfl(c, k + 1);
        int c2 = __shfl(c, k + 2), c3 = __shfl(c, k + 3);
        int c4 = __shfl(c, k + 4), c5 = __shfl(c, k + 5);
        int c6 = __shfl(c, k + 6), c7 = __shfl(c, k + 7);
        a0 += h0f[c0 * HG + lane]; a1 += h0f[c1 * HG + lane];
        a2 += h0f[c2 * HG + lane]; a3 += h0f[c3 * HG + lane];
        a4 += h0f[c4 * HG + lane]; a5 += h0f[c5 * HG + lane];
        a6 += h0f[c6 * HG + lane]; a7 += h0f[c7 * HG + lane];
      }
      for (; k < lim; k++) a0 += h0f[__shfl(c, k) * HG + lane];
    }
    aggL[nl][lane] = (((a0 + a1) + (a2 + a3)) + ((a4 + a5) + (a6 + a7))) * deg_inv[m0 + nl];
  }
  __syncthreads();

  // Phase B: waves 0,1 do the GEMM + LN + ReLU (split-bf16, 3-MFMA)
  if (wave < 2) {
    int mloc = wave * 16 + col16;
    int arow = m0 + mloc;
    f32x4 acc[4];
    #pragma unroll
    for (int nt = 0; nt < 4; nt++) acc[nt] = (f32x4){0.f, 0.f, 0.f, 0.f};

    // K 0..63: agg (LDS, split on the fly)
    #pragma unroll
    for (int kk = 0; kk < HG; kk += 32) {
      bf16x8 ah, al;
      #pragma unroll
      for (int j = 0; j < 8; j++) {
        float x = aggL[mloc][kk + quad * 8 + j];
        unsigned short hh = f2bf(x);
        ah[j] = (short)hh;
        al[j] = (short)f2bf(x - bf2f(hh));
      }
      #pragma unroll
      for (int nt = 0; nt < 4; nt++) {
        int n = nt * 16 + col16;
        bf16x8 bh = *(const bf16x8*)&Wchi[n * 128 + kk + quad * 8];
        bf16x8 bl = *(const bf16x8*)&Wclo[n * 128 + kk + quad * 8];
        acc[nt] = __builtin_amdgcn_mfma_f32_16x16x32_bf16(ah, bh, acc[nt], 0, 0, 0);
        acc[nt] = __builtin_amdgcn_mfma_f32_16x16x32_bf16(al, bh, acc[nt], 0, 0, 0);
        acc[nt] = __builtin_amdgcn_mfma_f32_16x16x32_bf16(ah, bl, acc[nt], 0, 0, 0);
      }
    }
    // K 64..127: h0 root (global fp32, split on the fly)
    #pragma unroll
    for (int kk = 0; kk < HG; kk += 32) {
      bf16x8 ah, al;
      #pragma unroll
      for (int j = 0; j < 8; j++) {
        float x = h0f[(size_t)arow * HG + kk + quad * 8 + j];
        unsigned short hh = f2bf(x);
        ah[j] = (short)hh;
        al[j] = (short)f2bf(x - bf2f(hh));
      }
      #pragma unroll
      for (int nt = 0; nt < 4; nt++) {
        int n = nt * 16 + col16;
        bf16x8 bh = *(const bf16x8*)&Wchi[n * 128 + 64 + kk + quad * 8];
        bf16x8 bl = *(const bf16x8*)&Wclo[n * 128 + 64 + kk + quad * 8];
        acc[nt] = __builtin_amdgcn_mfma_f32_16x16x32_bf16(ah, bh, acc[nt], 0, 0, 0);
        acc[nt] = __builtin_amdgcn_mfma_f32_16x16x32_bf16(al, bh, acc[nt], 0, 0, 0);
        acc[nt] = __builtin_amdgcn_mfma_f32_16x16x32_bf16(ah, bl, acc[nt], 0, 0, 0);
      }
    }

    float bias[4], gg[4], bb[4];
    #pragma unroll
    for (int nt = 0; nt < 4; nt++) {
      int n = nt * 16 + col16;
      bias[nt] = b1[n]; gg[nt] = g1[n]; bb[nt] = be1[n];
    }
    #pragma unroll
    for (int r = 0; r < 4; r++) {
      float v[4];
      #pragma unroll
      for (int nt = 0; nt < 4; nt++) v[nt] = acc[nt][r] + bias[nt];
      float s = (v[0] + v[1]) + (v[2] + v[3]);
      float mu = quad_sum16(s) * (1.f / 64.f);
      float sq = 0.f;
      #pragma unroll
      for (int nt = 0; nt < 4; nt++) { v[nt] -= mu; sq += v[nt] * v[nt]; }
      float var = quad_sum16(sq) * (1.f / 64.f);
      float rstd = rsqrtf(var + LN_EPS);
      int m = m0 + wave * 16 + quad * 4 + r;
      size_t base = ((size_t)t * NN + m) * HG;
      #pragma unroll
      for (int nt = 0; nt < 4; nt++) {
        float o = fmaxf(v[nt] * rstd * gg[nt] + bb[nt], 0.f);
        _Float16 hi = (_Float16)o;
        HtHi_all[base + nt * 16 + col16] = hi;
        HtLo_all[base + nt * 16 + col16] = (_Float16)(o - (float)hi);
      }
    }
  }
}

// ---------------- persistent GRU: all 16 steps in ONE kernel ----------------
// 625 blocks x 32 nodes. h state: fp32 in registers (16/lane), split-fp16 planes
// in LDS for MFMA A-operands. Whh fp16 fragments preloaded in registers (96 VGPR,
// reused 16x). Wih fp16 staged in LDS (padded stride 72). 2 barriers per step.
__global__ __launch_bounds__(256, 2) void k_gru_all(
    const _Float16* __restrict__ HtHi_all, const _Float16* __restrict__ HtLo_all,
    const _Float16* __restrict__ WihF,   // 384 x 64 fp16
    const _Float16* __restrict__ WhhF,   // 384 x 128 fp16
    const float* __restrict__ bih, const float* __restrict__ bhh,
    float* __restrict__ hout) {
  __shared__ _Float16 WihL[NG * 72];     // padded stride 72 (55.3 KB)
  __shared__ _Float16 hHiL[32 * 136];    // padded stride 136 (8.7 KB)
  __shared__ _Float16 hLoL[32 * 136];

  int tid = threadIdx.x;
  int lane = tid & 63, wave = tid >> 6;
  int col16 = lane & 15, quad = lane >> 4;
  int m0 = blockIdx.x * 32;
  int gb = 2 * wave;

  // stage Wih into LDS (16B chunks)
  for (int i = tid; i < NG * 64 / 8; i += 256) {
    int g = (i * 8) >> 6, k = (i * 8) & 63;
    *(f16x8*)&WihL[g * 72 + k] = *(const f16x8*)&WihF[g * 64 + k];
  }
  // zero h planes (h0 = 0)
  for (int i = tid; i < 32 * 136; i += 256) {
    hHiL[i] = (_Float16)0.f; hLoL[i] = (_Float16)0.f;
  }

  // wave's 6 gate tiles: r {2w,2w+1}, z {8+2w,9+2w}, n {16+2w,17+2w}
  int gts[6];
  #pragma unroll
  for (int t6 = 0; t6 < 6; t6++)
    gts[t6] = (t6 < 2) ? (gb + t6) : (t6 < 4) ? (8 + gb + t6 - 2) : (16 + gb + t6 - 4);

  // preload Whh fragments into registers (24 x f16x8 = 96 VGPR)
  f16x8 wgh[4][6];
  #pragma unroll
  for (int kk = 0; kk < 4; kk++)
    #pragma unroll
    for (int t6 = 0; t6 < 6; t6++)
      wgh[kk][t6] = *(const f16x8*)&WhhF[(size_t)(gts[t6] * 16 + col16) * HTT + kk * 32 + quad * 8];

  int jj[2]; float bR[2], bZ[2], bNi[2], bNh[2];
  #pragma unroll
  for (int js = 0; js < 2; js++) {
    int j = (gb + js) * 16 + col16;
    jj[js] = j;
    bR[js]  = bih[j] + bhh[j];
    bZ[js]  = bih[HTT + j] + bhh[HTT + j];
    bNi[js] = bih[2 * HTT + j];
    bNh[js] = bhh[2 * HTT + j];
  }
  float hreg[2][4][2];
  #pragma unroll
  for (int mt = 0; mt < 2; mt++)
    #pragma unroll
    for (int r = 0; r < 4; r++) { hreg[mt][r][0] = 0.f; hreg[mt][r][1] = 0.f; }

  __syncthreads();

  for (int t = 0; t < TS; t++) {
    f32x4 acc[8][2];
    #pragma unroll
    for (int a = 0; a < 8; a++) {
      acc[a][0] = (f32x4){0.f, 0.f, 0.f, 0.f};
      acc[a][1] = (f32x4){0.f, 0.f, 0.f, 0.f};
    }

    // gi: A = Ht[t] (global split-fp16), B = Wih (LDS)
    const _Float16* AH = HtHi_all + (size_t)t * NN * HG;
    const _Float16* AL = HtLo_all + (size_t)t * NN * HG;
    #pragma unroll
    for (int kk = 0; kk < HG; kk += 32) {
      f16x8 ah[2], al[2];
      #pragma unroll
      for (int mt = 0; mt < 2; mt++) {
        size_t o = (size_t)(m0 + mt * 16 + col16) * HG + kk + quad * 8;
        ah[mt] = *(const f16x8*)&AH[o];
        al[mt] = *(const f16x8*)&AL[o];
      }
      #pragma unroll
      for (int t6 = 0; t6 < 6; t6++) {
        f16x8 b = *(const f16x8*)&WihL[(gts[t6] * 16 + col16) * 72 + kk + quad * 8];
        #pragma unroll
        for (int mt = 0; mt < 2; mt++) {
          acc[t6][mt] = __builtin_amdgcn_mfma_f32_16x16x32_f16(ah[mt], b, acc[t6][mt], 0, 0, 0);
          acc[t6][mt] = __builtin_amdgcn_mfma_f32_16x16x32_f16(al[mt], b, acc[t6][mt], 0, 0, 0);
        }
      }
    }
    // gh: A = h planes (LDS), B = Whh (registers)
    #pragma unroll
    for (int kk = 0; kk < 4; kk++) {
      f16x8 ah[2], al[2];
      #pragma unroll
      for (int mt = 0; mt < 2; mt++) {
        int o = (mt * 16 + col16) * 136 + kk * 32 + quad * 8;
        ah[mt] = *(const f16x8*)&hHiL[o];
        al[mt] = *(const f16x8*)&hLoL[o];
      }
      #pragma unroll
      for (int t6 = 0; t6 < 6; t6++) {
        int ai = (t6 < 4) ? t6 : t6 + 2;   // n-part of gh -> acc[6],[7]
        #pragma unroll
        for (int mt = 0; mt < 2; mt++) {
          acc[ai][mt] = __builtin_amdgcn_mfma_f32_16x16x32_f16(ah[mt], wgh[kk][t6], acc[ai][mt], 0, 0, 0);
          acc[ai][mt] = __builtin_amdgcn_mfma_f32_16x16x32_f16(al[mt], wgh[kk][t6], acc[ai][mt], 0, 0, 0);
        }
      }
    }
    __syncthreads();   // all reads of h planes complete

    // gates in registers, write new h planes
    #pragma unroll
    for (int mt = 0; mt < 2; mt++) {
      #pragma unroll
      for (int r = 0; r < 4; r++) {
        int row = mt * 16 + quad * 4 + r;
        #pragma unroll
        for (int js = 0; js < 2; js++) {
          float R  = acc[0 + js][mt][r] + bR[js];
          float Z  = acc[2 + js][mt][r] + bZ[js];
          float Ni = acc[4 + js][mt][r] + bNi[js];
          float Nh = acc[6 + js][mt][r] + bNh[js];
          float rg = 1.f / (1.f + __expf(-R));
          float zg = 1.f / (1.f + __expf(-Z));
          float x = Ni + rg * Nh;
          float e = __expf(-2.f * fabsf(x));
          float th = (1.f - e) / (1.f + e);
          float nn = copysignf(th, x);
          float hn = (1.f - zg) * nn + zg * hreg[mt][r][js];
          hreg[mt][r][js] = hn;
          _Float16 hi = (_Float16)hn;
          hHiL[row * 136 + jj[js]] = hi;
          hLoL[row * 136 + jj[js]] = (_Float16)(hn - (float)hi);
        }
      }
    }
    __syncthreads();   // new h visible before next iteration's reads
  }

  // epilogue: write final h
  #pragma unroll
  for (int mt = 0; mt < 2; mt++)
    #pragma unroll
    for (int r = 0; r < 4; r++)
      #pragma unroll
      for (int js = 0; js < 2; js++)
        hout[(size_t)(m0 + mt * 16 + quad * 4 + r) * HTT + jj[js]] = hreg[mt][r][js];
}

// ---------------- head ----------------
__global__ __launch_bounds__(256) void k_head(
    const float* __restrict__ h, const float* __restrict__ hw,
    const float* __restrict__ hb, float* __restrict__ out) {
  int lane = threadIdx.x & 63;
  int n = blockIdx.x * 4 + (threadIdx.x >> 6);
  if (n >= NN) return;
  float v = h[n * HTT + lane] * hw[lane] + h[n * HTT + 64 + lane] * hw[64 + lane];
  v = wave_sum64(v);
  if (lane == 0) out[n] = v + hb[0];
}

extern "C" void kernel_launch(void* const* d_in, const int* in_sizes, int n_in,
                              void* d_out, int out_size, void* d_ws, size_t ws_size,
                              hipStream_t stream) {
  const float* x_seq = (const float*)d_in[0];
  const int*   edge  = (const int*)d_in[1];
  const float* Wl0   = (const float*)d_in[2];
  const float* Wr0   = (const float*)d_in[3];
  const float* b0    = (const float*)d_in[4];
  const float* g0    = (const float*)d_in[5];
  const float* be0   = (const float*)d_in[6];
  const float* Wl1   = (const float*)d_in[7];
  const float* Wr1   = (const float*)d_in[8];
  const float* b1    = (const float*)d_in[9];
  const float* g1    = (const float*)d_in[10];
  const float* be1   = (const float*)d_in[11];
  const float* Wih   = (const float*)d_in[12];
  const float* Whh   = (const float*)d_in[13];
  const float* bih   = (const float*)d_in[14];
  const float* bhh   = (const float*)d_in[15];
  const float* headW = (const float*)d_in[16];
  const float* headb = (const float*)d_in[17];
  float* out = (float*)d_out;

  const int* srcp = edge;
  const int* dstp = edge + NE;

  char* ws = (char*)d_ws;
  size_t off = 0;
  auto alloc = [&](size_t bytes) -> void* {
    void* p = ws + off;
    off += (bytes + 255) & ~(size_t)255;
    return p;
  };
  int*   cnt     = (int*)alloc(NN * 4);
  int*   row_ptr = (int*)alloc((NN + 1) * 4);
  int*   col     = (int*)alloc(NE * 4);
  float* deg_inv = (float*)alloc(NN * 4);
  float* h0f_all = (float*)alloc((size_t)TS * NN * HG * 4);        // 82 MB
  _Float16* HtHi_all = (_Float16*)alloc((size_t)TS * NN * HG * 2); // 41 MB
  _Float16* HtLo_all = (_Float16*)alloc((size_t)TS * NN * HG * 2); // 41 MB
  float* h       = (float*)alloc((size_t)NN * HTT * 4);            // 10 MB
  _Float16* WihF = (_Float16*)alloc((size_t)NG * HG * 2);
  _Float16* WhhF = (_Float16*)alloc((size_t)NG * HTT * 2);
  unsigned short* Wchi = (unsigned short*)alloc((size_t)HG * 128 * 2);
  unsigned short* Wclo = (unsigned short*)alloc((size_t)HG * 128 * 2);
  (void)ws_size; (void)in_sizes; (void)n_in; (void)out_size;

  k_init<<<(NN + 255) / 256, 256, 0, stream>>>(cnt);
  k_hist<<<(NE + 255) / 256, 256, 0, stream>>>(dstp, cnt);
  k_scan<<<1, 1024, 0, stream>>>(cnt, row_ptr, deg_inv);
  k_fill<<<(NE + 255) / 256, 256, 0, stream>>>(srcp, dstp, cnt, col);
  k_cvt_f16<<<(NG * HG + 255) / 256, 256, 0, stream>>>(Wih, WihF, NG * HG);
  k_cvt_f16<<<(NG * HTT + 255) / 256, 256, 0, stream>>>(Whh, WhhF, NG * HTT);
  k_cvt_sage<<<(HG * 128 + 255) / 256, 256, 0, stream>>>(Wl1, Wr1, Wchi, Wclo);

  k_sage0_all<<<dim3(5000, TS), 256, 0, stream>>>(x_seq, row_ptr, col, deg_inv,
                                                  Wl0, Wr0, b0, g0, be0, h0f_all);
  k_sage_all<<<dim3(NN / 32, TS), 256, 0, stream>>>(h0f_all, row_ptr, col, deg_inv,
                                                    Wchi, Wclo, b1, g1, be1,
                                                    HtHi_all, HtLo_all);
  k_gru_all<<<NN / 32, 256, 0, stream>>>(HtHi_all, HtLo_all, WihF, WhhF,
                                         bih, bhh, h);
  k_head<<<5000, 256, 0, stream>>>(h, headW, headb, out);
}

// Round 7
// 638.187 us; speedup vs baseline: 2.2373x; 1.0631x over previous
//
#include <hip/hip_runtime.h>
#include <math.h>

#define NN 20000
#define NE 320000
#define TS 16
#define HG 64
#define HTT 128
#define NG 384   // 3*HT
#define LN_EPS 1e-5f

typedef __attribute__((ext_vector_type(8))) _Float16 f16x8;
typedef __attribute__((ext_vector_type(4))) _Float16 f16x4;
typedef __attribute__((ext_vector_type(4))) float f32x4;

__device__ __forceinline__ float wave_sum64(float v) {
  #pragma unroll
  for (int off = 32; off > 0; off >>= 1) v += __shfl_xor(v, off, 64);
  return v;
}
__device__ __forceinline__ float quad_sum16(float v) {
  #pragma unroll
  for (int off = 1; off < 16; off <<= 1) v += __shfl_xor(v, off, 64);
  return v;
}

// ---------------- setup ----------------
__global__ void k_init(int* cnt) {
  int i = blockIdx.x * blockDim.x + threadIdx.x;
  if (i < NN) cnt[i] = 0;
}

__global__ void k_hist(const int* __restrict__ dst, int* cnt) {
  int e = blockIdx.x * blockDim.x + threadIdx.x;
  if (e < NE) atomicAdd(&cnt[dst[e]], 1);
}

__global__ void k_scan(int* cnt, int* row_ptr, float* deg_inv) {
  __shared__ int s[1024];
  int tid = threadIdx.x;
  int carry = 0;
  for (int base = 0; base < NN; base += 1024) {
    int n = base + tid;
    int v = (n < NN) ? cnt[n] : 0;
    s[tid] = v;
    __syncthreads();
    for (int off = 1; off < 1024; off <<= 1) {
      int t = (tid >= off) ? s[tid - off] : 0;
      __syncthreads();
      s[tid] += t;
      __syncthreads();
    }
    int incl = s[tid];
    if (n < NN) {
      int excl = carry + incl - v;
      row_ptr[n] = excl;
      cnt[n] = excl;
      deg_inv[n] = 1.0f / (float)((v > 1) ? v : 1);
    }
    carry += s[1023];
    __syncthreads();
  }
  if (tid == 0) row_ptr[NN] = carry;
}

__global__ void k_fill(const int* __restrict__ src, const int* __restrict__ dst,
                       int* cursor, int* col) {
  int e = blockIdx.x * blockDim.x + threadIdx.x;
  if (e < NE) {
    int p = atomicAdd(&cursor[dst[e]], 1);
    col[p] = src[e];
  }
}

__global__ void k_cvt_f16(const float* __restrict__ w, _Float16* __restrict__ o, int n) {
  int i = blockIdx.x * blockDim.x + threadIdx.x;
  if (i < n) o[i] = (_Float16)w[i];
}

// combined sage weight, transposed, split-fp16: Wc[n][k], k<64 -> Wl1[k][n], else Wr1
__global__ void k_cvt_sagef16(const float* __restrict__ Wl1, const float* __restrict__ Wr1,
                              _Float16* __restrict__ hi, _Float16* __restrict__ lo) {
  int i = blockIdx.x * blockDim.x + threadIdx.x;   // i = n*128 + k
  if (i < HG * 128) {
    int n = i >> 7, k = i & 127;
    float x = (k < HG) ? Wl1[k * HG + n] : Wr1[(k - HG) * HG + n];
    _Float16 h = (_Float16)x;
    hi[i] = h;
    lo[i] = (_Float16)(x - (float)h);
  }
}

// ---------------- agg0: scalar neighbor-mean of x, all (node,t) ----------------
// thread = (n,t): 16 consecutive threads share node n -> col[] reads broadcast.
__global__ __launch_bounds__(256) void k_agg0(
    const float* __restrict__ x_seq,
    const int* __restrict__ row_ptr, const int* __restrict__ col,
    const float* __restrict__ deg_inv,
    float* __restrict__ agg0) {     // agg0[n*16 + t]
  int tid = blockIdx.x * blockDim.x + threadIdx.x;
  int n = tid >> 4, t = tid & 15;
  if (n >= NN) return;
  const float* x_t = x_seq + (size_t)t * NN;
  int beg = row_ptr[n], end = row_ptr[n + 1];
  float s0 = 0.f, s1 = 0.f;
  int e = beg;
  for (; e + 2 <= end; e += 2) {
    s0 += x_t[col[e]];
    s1 += x_t[col[e + 1]];
  }
  if (e < end) s0 += x_t[col[e]];
  agg0[n * 16 + t] = (s0 + s1) * deg_inv[n];
}

// ---------------- ln0: lin + LN + ReLU -> h0 fp16, all (node,t) ----------------
// wave per (node,t); lane = feature.
__global__ __launch_bounds__(256) void k_ln0(
    const float* __restrict__ x_seq, const float* __restrict__ agg0,
    const float* __restrict__ Wl0, const float* __restrict__ Wr0,
    const float* __restrict__ b0,
    const float* __restrict__ g0, const float* __restrict__ be0,
    _Float16* __restrict__ h0h) {   // [t][n][64]
  int lane = threadIdx.x & 63;
  int w = blockIdx.x * 4 + (threadIdx.x >> 6);   // 0 .. NN*TS-1
  int t = w / NN, n = w - t * NN;
  float a = agg0[n * 16 + t];
  float xn = x_seq[(size_t)t * NN + n];
  float v = a * Wl0[lane] + xn * Wr0[lane] + b0[lane];
  float mu = wave_sum64(v) * (1.f / 64.f);
  float d = v - mu;
  float var = wave_sum64(d * d) * (1.f / 64.f);
  float o = d * rsqrtf(var + LN_EPS) * g0[lane] + be0[lane];
  h0h[(size_t)w * HG + lane] = (_Float16)fmaxf(o, 0.f);
}

// ---------------- SAGE layer 1: gather(fp16, 4-edge-parallel) + f16 MFMA + LN ----------------
// linear grid 10000 = 8 XCD-groups x 1250; swizzled so each XCD handles 2 timesteps.
__global__ __launch_bounds__(256) void k_sage_all(
    const _Float16* __restrict__ h0h,
    const int* __restrict__ row_ptr, const int* __restrict__ col,
    const float* __restrict__ deg_inv,
    const _Float16* __restrict__ Wchi, const _Float16* __restrict__ Wclo, // 64 x 128
    const float* __restrict__ b1, const float* __restrict__ g1, const float* __restrict__ be1,
    _Float16* __restrict__ HtHi_all, _Float16* __restrict__ HtLo_all) {
  __shared__ float aggL[32][68];
  // swizzle: xcd = b&7 gets timesteps {2*xcd, 2*xcd+1} (round-robin dispatch heuristic)
  int b = blockIdx.x;
  int xcd = b & 7, idx = b >> 3;          // idx 0..1249
  int half = (idx >= 625) ? 1 : 0;
  int t = xcd * 2 + half;
  int m0 = (idx - half * 625) * 32;

  const _Float16* h0t = h0h + (size_t)t * NN * HG;
  int tid = threadIdx.x;
  int lane = tid & 63, wave = tid >> 6;
  int col16 = lane & 15, quad = lane >> 4;
  int grp = lane >> 4;                    // 4 edge-groups of 16 lanes
  int f4 = (lane & 15) * 4;               // feature base

  // Phase A: each wave gathers 8 nodes; 4 edges in parallel, 2-deep unroll
  for (int i = 0; i < 8; i++) {
    int nl = wave * 8 + i;
    int n = m0 + nl;
    int beg = row_ptr[n], end = row_ptr[n + 1];
    int deg = end - beg;
    float a00 = 0.f, a01 = 0.f, a02 = 0.f, a03 = 0.f;
    float a10 = 0.f, a11 = 0.f, a12 = 0.f, a13 = 0.f;
    for (int base = 0; base < deg; base += 64) {
      int lim = deg - base; if (lim > 64) lim = 64;
      int cvec = (base + lane < deg) ? col[beg + base + lane] : 0;
      for (int k = 0; k < lim; k += 8) {
        int e0 = k + grp, e1 = k + 4 + grp;
        int c0 = __shfl(cvec, e0), c1 = __shfl(cvec, e1);
        if (e0 < lim) {
          f16x4 v = *(const f16x4*)&h0t[c0 * HG + f4];
          a00 += (float)v.x; a01 += (float)v.y; a02 += (float)v.z; a03 += (float)v.w;
        }
        if (e1 < lim) {
          f16x4 v = *(const f16x4*)&h0t[c1 * HG + f4];
          a10 += (float)v.x; a11 += (float)v.y; a12 += (float)v.z; a13 += (float)v.w;
        }
      }
    }
    float s0 = a00 + a10, s1 = a01 + a11, s2 = a02 + a12, s3 = a03 + a13;
    s0 += __shfl_xor(s0, 16, 64); s0 += __shfl_xor(s0, 32, 64);
    s1 += __shfl_xor(s1, 16, 64); s1 += __shfl_xor(s1, 32, 64);
    s2 += __shfl_xor(s2, 16, 64); s2 += __shfl_xor(s2, 32, 64);
    s3 += __shfl_xor(s3, 16, 64); s3 += __shfl_xor(s3, 32, 64);
    if (grp == 0) {
      float di = deg_inv[n];
      aggL[nl][f4 + 0] = s0 * di;
      aggL[nl][f4 + 1] = s1 * di;
      aggL[nl][f4 + 2] = s2 * di;
      aggL[nl][f4 + 3] = s3 * di;
    }
  }
  __syncthreads();

  // Phase B: waves 0,1: C = [agg | h0] @ Wc^T via f16 MFMA + bias + LN + ReLU
  if (wave < 2) {
    int mloc = wave * 16 + col16;
    int arow = m0 + mloc;
    f32x4 acc[4];
    #pragma unroll
    for (int nt = 0; nt < 4; nt++) acc[nt] = (f32x4){0.f, 0.f, 0.f, 0.f};

    // K 0..63: agg (LDS fp32, split to fp16 hi+lo; 3 MFMAs)
    #pragma unroll
    for (int kk = 0; kk < HG; kk += 32) {
      f16x8 ah, al;
      #pragma unroll
      for (int j = 0; j < 8; j++) {
        float x = aggL[mloc][kk + quad * 8 + j];
        _Float16 h = (_Float16)x;
        ah[j] = h;
        al[j] = (_Float16)(x - (float)h);
      }
      #pragma unroll
      for (int nt = 0; nt < 4; nt++) {
        int n = nt * 16 + col16;
        f16x8 bh = *(const f16x8*)&Wchi[n * 128 + kk + quad * 8];
        f16x8 bl = *(const f16x8*)&Wclo[n * 128 + kk + quad * 8];
        acc[nt] = __builtin_amdgcn_mfma_f32_16x16x32_f16(ah, bh, acc[nt], 0, 0, 0);
        acc[nt] = __builtin_amdgcn_mfma_f32_16x16x32_f16(al, bh, acc[nt], 0, 0, 0);
        acc[nt] = __builtin_amdgcn_mfma_f32_16x16x32_f16(ah, bl, acc[nt], 0, 0, 0);
      }
    }
    // K 64..127: h0 root (fp16 exact, residual 0; 2 MFMAs)
    #pragma unroll
    for (int kk = 0; kk < HG; kk += 32) {
      f16x8 ah = *(const f16x8*)&h0t[(size_t)arow * HG + kk + quad * 8];
      #pragma unroll
      for (int nt = 0; nt < 4; nt++) {
        int n = nt * 16 + col16;
        f16x8 bh = *(const f16x8*)&Wchi[n * 128 + 64 + kk + quad * 8];
        f16x8 bl = *(const f16x8*)&Wclo[n * 128 + 64 + kk + quad * 8];
        acc[nt] = __builtin_amdgcn_mfma_f32_16x16x32_f16(ah, bh, acc[nt], 0, 0, 0);
        acc[nt] = __builtin_amdgcn_mfma_f32_16x16x32_f16(ah, bl, acc[nt], 0, 0, 0);
      }
    }

    float bias[4], gg[4], bb[4];
    #pragma unroll
    for (int nt = 0; nt < 4; nt++) {
      int n = nt * 16 + col16;
      bias[nt] = b1[n]; gg[nt] = g1[n]; bb[nt] = be1[n];
    }
    #pragma unroll
    for (int r = 0; r < 4; r++) {
      float v[4];
      #pragma unroll
      for (int nt = 0; nt < 4; nt++) v[nt] = acc[nt][r] + bias[nt];
      float s = (v[0] + v[1]) + (v[2] + v[3]);
      float mu = quad_sum16(s) * (1.f / 64.f);
      float sq = 0.f;
      #pragma unroll
      for (int nt = 0; nt < 4; nt++) { v[nt] -= mu; sq += v[nt] * v[nt]; }
      float var = quad_sum16(sq) * (1.f / 64.f);
      float rstd = rsqrtf(var + LN_EPS);
      int m = m0 + wave * 16 + quad * 4 + r;
      size_t base = ((size_t)t * NN + m) * HG;
      #pragma unroll
      for (int nt = 0; nt < 4; nt++) {
        float o = fmaxf(v[nt] * rstd * gg[nt] + bb[nt], 0.f);
        _Float16 hi = (_Float16)o;
        HtHi_all[base + nt * 16 + col16] = hi;
        HtLo_all[base + nt * 16 + col16] = (_Float16)(o - (float)hi);
      }
    }
  }
}

// ---------------- persistent GRU: all 16 steps in ONE kernel ----------------
__global__ __launch_bounds__(256, 2) void k_gru_all(
    const _Float16* __restrict__ HtHi_all, const _Float16* __restrict__ HtLo_all,
    const _Float16* __restrict__ WihF,   // 384 x 64 fp16
    const _Float16* __restrict__ WhhF,   // 384 x 128 fp16
    const float* __restrict__ bih, const float* __restrict__ bhh,
    float* __restrict__ hout) {
  __shared__ _Float16 WihL[NG * 72];     // padded stride 72 (55.3 KB)
  __shared__ _Float16 hHiL[32 * 136];    // padded stride 136
  __shared__ _Float16 hLoL[32 * 136];

  int tid = threadIdx.x;
  int lane = tid & 63, wave = tid >> 6;
  int col16 = lane & 15, quad = lane >> 4;
  int m0 = blockIdx.x * 32;
  int gb = 2 * wave;

  for (int i = tid; i < NG * 64 / 8; i += 256) {
    int g = (i * 8) >> 6, k = (i * 8) & 63;
    *(f16x8*)&WihL[g * 72 + k] = *(const f16x8*)&WihF[g * 64 + k];
  }
  for (int i = tid; i < 32 * 136; i += 256) {
    hHiL[i] = (_Float16)0.f; hLoL[i] = (_Float16)0.f;
  }

  int gts[6];
  #pragma unroll
  for (int t6 = 0; t6 < 6; t6++)
    gts[t6] = (t6 < 2) ? (gb + t6) : (t6 < 4) ? (8 + gb + t6 - 2) : (16 + gb + t6 - 4);

  f16x8 wgh[4][6];
  #pragma unroll
  for (int kk = 0; kk < 4; kk++)
    #pragma unroll
    for (int t6 = 0; t6 < 6; t6++)
      wgh[kk][t6] = *(const f16x8*)&WhhF[(size_t)(gts[t6] * 16 + col16) * HTT + kk * 32 + quad * 8];

  int jj[2]; float bR[2], bZ[2], bNi[2], bNh[2];
  #pragma unroll
  for (int js = 0; js < 2; js++) {
    int j = (gb + js) * 16 + col16;
    jj[js] = j;
    bR[js]  = bih[j] + bhh[j];
    bZ[js]  = bih[HTT + j] + bhh[HTT + j];
    bNi[js] = bih[2 * HTT + j];
    bNh[js] = bhh[2 * HTT + j];
  }
  float hreg[2][4][2];
  #pragma unroll
  for (int mt = 0; mt < 2; mt++)
    #pragma unroll
    for (int r = 0; r < 4; r++) { hreg[mt][r][0] = 0.f; hreg[mt][r][1] = 0.f; }

  __syncthreads();

  for (int t = 0; t < TS; t++) {
    f32x4 acc[8][2];
    #pragma unroll
    for (int a = 0; a < 8; a++) {
      acc[a][0] = (f32x4){0.f, 0.f, 0.f, 0.f};
      acc[a][1] = (f32x4){0.f, 0.f, 0.f, 0.f};
    }

    const _Float16* AH = HtHi_all + (size_t)t * NN * HG;
    const _Float16* AL = HtLo_all + (size_t)t * NN * HG;
    #pragma unroll
    for (int kk = 0; kk < HG; kk += 32) {
      f16x8 ah[2], al[2];
      #pragma unroll
      for (int mt = 0; mt < 2; mt++) {
        size_t o = (size_t)(m0 + mt * 16 + col16) * HG + kk + quad * 8;
        ah[mt] = *(const f16x8*)&AH[o];
        al[mt] = *(const f16x8*)&AL[o];
      }
      #pragma unroll
      for (int t6 = 0; t6 < 6; t6++) {
        f16x8 b = *(const f16x8*)&WihL[(gts[t6] * 16 + col16) * 72 + kk + quad * 8];
        #pragma unroll
        for (int mt = 0; mt < 2; mt++) {
          acc[t6][mt] = __builtin_amdgcn_mfma_f32_16x16x32_f16(ah[mt], b, acc[t6][mt], 0, 0, 0);
          acc[t6][mt] = __builtin_amdgcn_mfma_f32_16x16x32_f16(al[mt], b, acc[t6][mt], 0, 0, 0);
        }
      }
    }
    #pragma unroll
    for (int kk = 0; kk < 4; kk++) {
      f16x8 ah[2], al[2];
      #pragma unroll
      for (int mt = 0; mt < 2; mt++) {
        int o = (mt * 16 + col16) * 136 + kk * 32 + quad * 8;
        ah[mt] = *(const f16x8*)&hHiL[o];
        al[mt] = *(const f16x8*)&hLoL[o];
      }
      #pragma unroll
      for (int t6 = 0; t6 < 6; t6++) {
        int ai = (t6 < 4) ? t6 : t6 + 2;
        #pragma unroll
        for (int mt = 0; mt < 2; mt++) {
          acc[ai][mt] = __builtin_amdgcn_mfma_f32_16x16x32_f16(ah[mt], wgh[kk][t6], acc[ai][mt], 0, 0, 0);
          acc[ai][mt] = __builtin_amdgcn_mfma_f32_16x16x32_f16(al[mt], wgh[kk][t6], acc[ai][mt], 0, 0, 0);
        }
      }
    }
    __syncthreads();

    #pragma unroll
    for (int mt = 0; mt < 2; mt++) {
      #pragma unroll
      for (int r = 0; r < 4; r++) {
        int row = mt * 16 + quad * 4 + r;
        #pragma unroll
        for (int js = 0; js < 2; js++) {
          float R  = acc[0 + js][mt][r] + bR[js];
          float Z  = acc[2 + js][mt][r] + bZ[js];
          float Ni = acc[4 + js][mt][r] + bNi[js];
          float Nh = acc[6 + js][mt][r] + bNh[js];
          float rg = 1.f / (1.f + __expf(-R));
          float zg = 1.f / (1.f + __expf(-Z));
          float x = Ni + rg * Nh;
          float e = __expf(-2.f * fabsf(x));
          float th = (1.f - e) / (1.f + e);
          float nn = copysignf(th, x);
          float hn = (1.f - zg) * nn + zg * hreg[mt][r][js];
          hreg[mt][r][js] = hn;
          _Float16 hi = (_Float16)hn;
          hHiL[row * 136 + jj[js]] = hi;
          hLoL[row * 136 + jj[js]] = (_Float16)(hn - (float)hi);
        }
      }
    }
    __syncthreads();
  }

  #pragma unroll
  for (int mt = 0; mt < 2; mt++)
    #pragma unroll
    for (int r = 0; r < 4; r++)
      #pragma unroll
      for (int js = 0; js < 2; js++)
        hout[(size_t)(m0 + mt * 16 + quad * 4 + r) * HTT + jj[js]] = hreg[mt][r][js];
}

// ---------------- head ----------------
__global__ __launch_bounds__(256) void k_head(
    const float* __restrict__ h, const float* __restrict__ hw,
    const float* __restrict__ hb, float* __restrict__ out) {
  int lane = threadIdx.x & 63;
  int n = blockIdx.x * 4 + (threadIdx.x >> 6);
  if (n >= NN) return;
  float v = h[n * HTT + lane] * hw[lane] + h[n * HTT + 64 + lane] * hw[64 + lane];
  v = wave_sum64(v);
  if (lane == 0) out[n] = v + hb[0];
}

extern "C" void kernel_launch(void* const* d_in, const int* in_sizes, int n_in,
                              void* d_out, int out_size, void* d_ws, size_t ws_size,
                              hipStream_t stream) {
  const float* x_seq = (const float*)d_in[0];
  const int*   edge  = (const int*)d_in[1];
  const float* Wl0   = (const float*)d_in[2];
  const float* Wr0   = (const float*)d_in[3];
  const float* b0    = (const float*)d_in[4];
  const float* g0    = (const float*)d_in[5];
  const float* be0   = (const float*)d_in[6];
  const float* Wl1   = (const float*)d_in[7];
  const float* Wr1   = (const float*)d_in[8];
  const float* b1    = (const float*)d_in[9];
  const float* g1    = (const float*)d_in[10];
  const float* be1   = (const float*)d_in[11];
  const float* Wih   = (const float*)d_in[12];
  const float* Whh   = (const float*)d_in[13];
  const float* bih   = (const float*)d_in[14];
  const float* bhh   = (const float*)d_in[15];
  const float* headW = (const float*)d_in[16];
  const float* headb = (const float*)d_in[17];
  float* out = (float*)d_out;

  const int* srcp = edge;
  const int* dstp = edge + NE;

  char* ws = (char*)d_ws;
  size_t off = 0;
  auto alloc = [&](size_t bytes) -> void* {
    void* p = ws + off;
    off += (bytes + 255) & ~(size_t)255;
    return p;
  };
  int*   cnt     = (int*)alloc(NN * 4);
  int*   row_ptr = (int*)alloc((NN + 1) * 4);
  int*   col     = (int*)alloc(NE * 4);
  float* deg_inv = (float*)alloc(NN * 4);
  float* agg0    = (float*)alloc((size_t)NN * TS * 4);             // 1.3 MB
  _Float16* h0h  = (_Float16*)alloc((size_t)TS * NN * HG * 2);     // 41 MB
  _Float16* HtHi_all = (_Float16*)alloc((size_t)TS * NN * HG * 2); // 41 MB
  _Float16* HtLo_all = (_Float16*)alloc((size_t)TS * NN * HG * 2); // 41 MB
  float* h       = (float*)alloc((size_t)NN * HTT * 4);            // 10 MB
  _Float16* WihF = (_Float16*)alloc((size_t)NG * HG * 2);
  _Float16* WhhF = (_Float16*)alloc((size_t)NG * HTT * 2);
  _Float16* Wchi = (_Float16*)alloc((size_t)HG * 128 * 2);
  _Float16* Wclo = (_Float16*)alloc((size_t)HG * 128 * 2);
  (void)ws_size; (void)in_sizes; (void)n_in; (void)out_size;

  k_init<<<(NN + 255) / 256, 256, 0, stream>>>(cnt);
  k_hist<<<(NE + 255) / 256, 256, 0, stream>>>(dstp, cnt);
  k_scan<<<1, 1024, 0, stream>>>(cnt, row_ptr, deg_inv);
  k_fill<<<(NE + 255) / 256, 256, 0, stream>>>(srcp, dstp, cnt, col);
  k_cvt_f16<<<(NG * HG + 255) / 256, 256, 0, stream>>>(Wih, WihF, NG * HG);
  k_cvt_f16<<<(NG * HTT + 255) / 256, 256, 0, stream>>>(Whh, WhhF, NG * HTT);
  k_cvt_sagef16<<<(HG * 128 + 255) / 256, 256, 0, stream>>>(Wl1, Wr1, Wchi, Wclo);

  k_agg0<<<NN * TS / 256, 256, 0, stream>>>(x_seq, row_ptr, col, deg_inv, agg0);
  k_ln0<<<NN * TS / 4, 256, 0, stream>>>(x_seq, agg0, Wl0, Wr0, b0, g0, be0, h0h);
  k_sage_all<<<(NN / 32) * TS, 256, 0, stream>>>(h0h, row_ptr, col, deg_inv,
                                                 Wchi, Wclo, b1, g1, be1,
                                                 HtHi_all, HtLo_all);
  k_gru_all<<<NN / 32, 256, 0, stream>>>(HtHi_all, HtLo_all, WihF, WhhF,
                                         bih, bhh, h);
  k_head<<<5000, 256, 0, stream>>>(h, headW, headb, out);
}

// Round 8
// 612.574 us; speedup vs baseline: 2.3309x; 1.0418x over previous
//
#include <hip/hip_runtime.h>
#include <math.h>

#define NN 20000
#define NE 320000
#define TS 16
#define HG 64
#define HTT 128
#define NG 384   // 3*HT
#define LN_EPS 1e-5f

typedef __attribute__((ext_vector_type(8))) _Float16 f16x8;
typedef __attribute__((ext_vector_type(4))) _Float16 f16x4;
typedef __attribute__((ext_vector_type(4))) float f32x4;

__device__ __forceinline__ float wave_sum64(float v) {
  #pragma unroll
  for (int off = 32; off > 0; off >>= 1) v += __shfl_xor(v, off, 64);
  return v;
}
__device__ __forceinline__ float quad_sum16(float v) {
  #pragma unroll
  for (int off = 1; off < 16; off <<= 1) v += __shfl_xor(v, off, 64);
  return v;
}

// ---------------- setup ----------------
__global__ void k_init(int* cnt) {
  int i = blockIdx.x * blockDim.x + threadIdx.x;
  if (i < NN) cnt[i] = 0;
}

__global__ void k_hist(const int* __restrict__ dst, int* cnt) {
  int e = blockIdx.x * blockDim.x + threadIdx.x;
  if (e < NE) atomicAdd(&cnt[dst[e]], 1);
}

__global__ void k_scan(int* cnt, int* row_ptr, float* deg_inv) {
  __shared__ int s[1024];
  int tid = threadIdx.x;
  int carry = 0;
  for (int base = 0; base < NN; base += 1024) {
    int n = base + tid;
    int v = (n < NN) ? cnt[n] : 0;
    s[tid] = v;
    __syncthreads();
    for (int off = 1; off < 1024; off <<= 1) {
      int t = (tid >= off) ? s[tid - off] : 0;
      __syncthreads();
      s[tid] += t;
      __syncthreads();
    }
    int incl = s[tid];
    if (n < NN) {
      int excl = carry + incl - v;
      row_ptr[n] = excl;
      cnt[n] = excl;
      deg_inv[n] = 1.0f / (float)((v > 1) ? v : 1);
    }
    carry += s[1023];
    __syncthreads();
  }
  if (tid == 0) row_ptr[NN] = carry;
}

__global__ void k_fill(const int* __restrict__ src, const int* __restrict__ dst,
                       int* cursor, int* col) {
  int e = blockIdx.x * blockDim.x + threadIdx.x;
  if (e < NE) {
    int p = atomicAdd(&cursor[dst[e]], 1);
    col[p] = src[e];
  }
}

__global__ void k_cvt_f16(const float* __restrict__ w, _Float16* __restrict__ o, int n) {
  int i = blockIdx.x * blockDim.x + threadIdx.x;
  if (i < n) o[i] = (_Float16)w[i];
}

// combined sage weight, transposed, split-fp16: Wc[n][k], k<64 -> Wl1[k][n], else Wr1
__global__ void k_cvt_sagef16(const float* __restrict__ Wl1, const float* __restrict__ Wr1,
                              _Float16* __restrict__ hi, _Float16* __restrict__ lo) {
  int i = blockIdx.x * blockDim.x + threadIdx.x;   // i = n*128 + k
  if (i < HG * 128) {
    int n = i >> 7, k = i & 127;
    float x = (k < HG) ? Wl1[k * HG + n] : Wr1[(k - HG) * HG + n];
    _Float16 h = (_Float16)x;
    hi[i] = h;
    lo[i] = (_Float16)(x - (float)h);
  }
}

// ---------------- agg0: scalar neighbor-mean of x, all (node,t) ----------------
__global__ __launch_bounds__(256) void k_agg0(
    const float* __restrict__ x_seq,
    const int* __restrict__ row_ptr, const int* __restrict__ col,
    const float* __restrict__ deg_inv,
    float* __restrict__ agg0) {     // agg0[n*16 + t]
  int tid = blockIdx.x * blockDim.x + threadIdx.x;
  int n = tid >> 4, t = tid & 15;
  if (n >= NN) return;
  const float* x_t = x_seq + (size_t)t * NN;
  int beg = row_ptr[n], end = row_ptr[n + 1];
  float s0 = 0.f, s1 = 0.f;
  int e = beg;
  for (; e + 2 <= end; e += 2) {
    s0 += x_t[col[e]];
    s1 += x_t[col[e + 1]];
  }
  if (e < end) s0 += x_t[col[e]];
  agg0[n * 16 + t] = (s0 + s1) * deg_inv[n];
}

// ---------------- ln0: lin + LN + ReLU -> h0 fp16, all (node,t) ----------------
__global__ __launch_bounds__(256) void k_ln0(
    const float* __restrict__ x_seq, const float* __restrict__ agg0,
    const float* __restrict__ Wl0, const float* __restrict__ Wr0,
    const float* __restrict__ b0,
    const float* __restrict__ g0, const float* __restrict__ be0,
    _Float16* __restrict__ h0h) {   // [t][n][64]
  int lane = threadIdx.x & 63;
  int w = blockIdx.x * 4 + (threadIdx.x >> 6);   // 0 .. NN*TS-1
  int t = w / NN, n = w - t * NN;
  float a = agg0[n * 16 + t];
  float xn = x_seq[(size_t)t * NN + n];
  float v = a * Wl0[lane] + xn * Wr0[lane] + b0[lane];
  float mu = wave_sum64(v) * (1.f / 64.f);
  float d = v - mu;
  float var = wave_sum64(d * d) * (1.f / 64.f);
  float o = d * rsqrtf(var + LN_EPS) * g0[lane] + be0[lane];
  h0h[(size_t)w * HG + lane] = (_Float16)fmaxf(o, 0.f);
}

// ---------------- SAGE layer 1: branch-free gather + f16 MFMA + LN ----------------
// linear grid 10000 = 8 XCD-groups x 1250; swizzled so each XCD handles 2 timesteps
// (one at a time: ws 2.56 MB fits per-XCD L2 -> FETCH ~= cold only, verified R7).
__global__ __launch_bounds__(256) void k_sage_all(
    const _Float16* __restrict__ h0h,
    const int* __restrict__ row_ptr, const int* __restrict__ col,
    const float* __restrict__ deg_inv,
    const _Float16* __restrict__ Wchi, const _Float16* __restrict__ Wclo, // 64 x 128
    const float* __restrict__ b1, const float* __restrict__ g1, const float* __restrict__ be1,
    _Float16* __restrict__ HtHi_all, _Float16* __restrict__ HtLo_all) {
  __shared__ float aggL[32][68];
  int b = blockIdx.x;
  int xcd = b & 7, idx = b >> 3;          // idx 0..1249
  int half = (idx >= 625) ? 1 : 0;
  int t = xcd * 2 + half;
  int m0 = (idx - half * 625) * 32;

  const _Float16* h0t = h0h + (size_t)t * NN * HG;
  int tid = threadIdx.x;
  int lane = tid & 63, wave = tid >> 6;
  int col16 = lane & 15, quad = lane >> 4;
  int grp = lane >> 4;                    // 4 edge-groups of 16 lanes
  int f4 = (lane & 15) * 4;               // feature base

  const f16x4 zero4 = {(_Float16)0.f, (_Float16)0.f, (_Float16)0.f, (_Float16)0.f};

  // Phase A: each wave gathers 8 nodes; 8 edges/iter, branch-free, shfl-free.
  // Group g handles edges g, g+4, g+8, ... ; invalid slots select index 0 and
  // zero the loaded data via cndmask. Accumulate in packed fp16 (2 partials,
  // <=8 terms each -> error ~1e-3 pre-mean, ~1e-4 post-mean: safe).
  for (int i = 0; i < 8; i++) {
    int nl = wave * 8 + i;
    int n = m0 + nl;
    int beg = row_ptr[n];
    int deg = row_ptr[n + 1] - beg;
    f16x4 acc0 = zero4, acc1 = zero4;
    int ev0 = grp, ev1 = grp + 4;
    int iters = (deg + 7) >> 3;
    for (int it = 0; it < iters; it++) {
      bool v0 = ev0 < deg, v1 = ev1 < deg;
      int i0 = v0 ? ev0 : 0, i1 = v1 ? ev1 : 0;
      int c0 = col[beg + i0];             // 16 lanes same addr -> broadcast
      int c1 = col[beg + i1];
      f16x4 d0 = *(const f16x4*)&h0t[c0 * HG + f4];
      f16x4 d1 = *(const f16x4*)&h0t[c1 * HG + f4];
      d0 = v0 ? d0 : zero4;               // cndmask, no branch
      d1 = v1 ? d1 : zero4;
      acc0 += d0;                         // v_pk_add_f16
      acc1 += d1;
      ev0 += 8; ev1 += 8;
    }
    f16x4 sv = acc0 + acc1;
    float s0 = (float)sv.x, s1 = (float)sv.y, s2 = (float)sv.z, s3 = (float)sv.w;
    s0 += __shfl_xor(s0, 16, 64); s0 += __shfl_xor(s0, 32, 64);
    s1 += __shfl_xor(s1, 16, 64); s1 += __shfl_xor(s1, 32, 64);
    s2 += __shfl_xor(s2, 16, 64); s2 += __shfl_xor(s2, 32, 64);
    s3 += __shfl_xor(s3, 16, 64); s3 += __shfl_xor(s3, 32, 64);
    if (grp == 0) {
      float di = deg_inv[n];
      aggL[nl][f4 + 0] = s0 * di;
      aggL[nl][f4 + 1] = s1 * di;
      aggL[nl][f4 + 2] = s2 * di;
      aggL[nl][f4 + 3] = s3 * di;
    }
  }
  __syncthreads();

  // Phase B: waves 0,1: C = [agg | h0] @ Wc^T via f16 MFMA + bias + LN + ReLU
  if (wave < 2) {
    int mloc = wave * 16 + col16;
    int arow = m0 + mloc;
    f32x4 acc[4];
    #pragma unroll
    for (int nt = 0; nt < 4; nt++) acc[nt] = (f32x4){0.f, 0.f, 0.f, 0.f};

    // K 0..63: agg (LDS fp32, split to fp16 hi+lo; 3 MFMAs)
    #pragma unroll
    for (int kk = 0; kk < HG; kk += 32) {
      f16x8 ah, al;
      #pragma unroll
      for (int j = 0; j < 8; j++) {
        float x = aggL[mloc][kk + quad * 8 + j];
        _Float16 h = (_Float16)x;
        ah[j] = h;
        al[j] = (_Float16)(x - (float)h);
      }
      #pragma unroll
      for (int nt = 0; nt < 4; nt++) {
        int n = nt * 16 + col16;
        f16x8 bh = *(const f16x8*)&Wchi[n * 128 + kk + quad * 8];
        f16x8 bl = *(const f16x8*)&Wclo[n * 128 + kk + quad * 8];
        acc[nt] = __builtin_amdgcn_mfma_f32_16x16x32_f16(ah, bh, acc[nt], 0, 0, 0);
        acc[nt] = __builtin_amdgcn_mfma_f32_16x16x32_f16(al, bh, acc[nt], 0, 0, 0);
        acc[nt] = __builtin_amdgcn_mfma_f32_16x16x32_f16(ah, bl, acc[nt], 0, 0, 0);
      }
    }
    // K 64..127: h0 root (fp16 exact, residual 0; 2 MFMAs)
    #pragma unroll
    for (int kk = 0; kk < HG; kk += 32) {
      f16x8 ah = *(const f16x8*)&h0t[(size_t)arow * HG + kk + quad * 8];
      #pragma unroll
      for (int nt = 0; nt < 4; nt++) {
        int n = nt * 16 + col16;
        f16x8 bh = *(const f16x8*)&Wchi[n * 128 + 64 + kk + quad * 8];
        f16x8 bl = *(const f16x8*)&Wclo[n * 128 + 64 + kk + quad * 8];
        acc[nt] = __builtin_amdgcn_mfma_f32_16x16x32_f16(ah, bh, acc[nt], 0, 0, 0);
        acc[nt] = __builtin_amdgcn_mfma_f32_16x16x32_f16(ah, bl, acc[nt], 0, 0, 0);
      }
    }

    float bias[4], gg[4], bb[4];
    #pragma unroll
    for (int nt = 0; nt < 4; nt++) {
      int n = nt * 16 + col16;
      bias[nt] = b1[n]; gg[nt] = g1[n]; bb[nt] = be1[n];
    }
    #pragma unroll
    for (int r = 0; r < 4; r++) {
      float v[4];
      #pragma unroll
      for (int nt = 0; nt < 4; nt++) v[nt] = acc[nt][r] + bias[nt];
      float s = (v[0] + v[1]) + (v[2] + v[3]);
      float mu = quad_sum16(s) * (1.f / 64.f);
      float sq = 0.f;
      #pragma unroll
      for (int nt = 0; nt < 4; nt++) { v[nt] -= mu; sq += v[nt] * v[nt]; }
      float var = quad_sum16(sq) * (1.f / 64.f);
      float rstd = rsqrtf(var + LN_EPS);
      int m = m0 + wave * 16 + quad * 4 + r;
      size_t base = ((size_t)t * NN + m) * HG;
      #pragma unroll
      for (int nt = 0; nt < 4; nt++) {
        float o = fmaxf(v[nt] * rstd * gg[nt] + bb[nt], 0.f);
        _Float16 hi = (_Float16)o;
        HtHi_all[base + nt * 16 + col16] = hi;
        HtLo_all[base + nt * 16 + col16] = (_Float16)(o - (float)hi);
      }
    }
  }
}

// ---------------- persistent GRU: all 16 steps in ONE kernel ----------------
// Pipeline: issue Ht[t] global loads first, run gh (LDS) MFMAs to hide their
// latency, then gi MFMAs consume them.
__global__ __launch_bounds__(256, 2) void k_gru_all(
    const _Float16* __restrict__ HtHi_all, const _Float16* __restrict__ HtLo_all,
    const _Float16* __restrict__ WihF,   // 384 x 64 fp16
    const _Float16* __restrict__ WhhF,   // 384 x 128 fp16
    const float* __restrict__ bih, const float* __restrict__ bhh,
    float* __restrict__ hout) {
  __shared__ _Float16 WihL[NG * 72];     // padded stride 72 (55.3 KB)
  __shared__ _Float16 hHiL[32 * 136];    // padded stride 136
  __shared__ _Float16 hLoL[32 * 136];

  int tid = threadIdx.x;
  int lane = tid & 63, wave = tid >> 6;
  int col16 = lane & 15, quad = lane >> 4;
  int m0 = blockIdx.x * 32;
  int gb = 2 * wave;

  for (int i = tid; i < NG * 64 / 8; i += 256) {
    int g = (i * 8) >> 6, k = (i * 8) & 63;
    *(f16x8*)&WihL[g * 72 + k] = *(const f16x8*)&WihF[g * 64 + k];
  }
  for (int i = tid; i < 32 * 136; i += 256) {
    hHiL[i] = (_Float16)0.f; hLoL[i] = (_Float16)0.f;
  }

  int gts[6];
  #pragma unroll
  for (int t6 = 0; t6 < 6; t6++)
    gts[t6] = (t6 < 2) ? (gb + t6) : (t6 < 4) ? (8 + gb + t6 - 2) : (16 + gb + t6 - 4);

  f16x8 wgh[4][6];
  #pragma unroll
  for (int kk = 0; kk < 4; kk++)
    #pragma unroll
    for (int t6 = 0; t6 < 6; t6++)
      wgh[kk][t6] = *(const f16x8*)&WhhF[(size_t)(gts[t6] * 16 + col16) * HTT + kk * 32 + quad * 8];

  int jj[2]; float bR[2], bZ[2], bNi[2], bNh[2];
  #pragma unroll
  for (int js = 0; js < 2; js++) {
    int j = (gb + js) * 16 + col16;
    jj[js] = j;
    bR[js]  = bih[j] + bhh[j];
    bZ[js]  = bih[HTT + j] + bhh[HTT + j];
    bNi[js] = bih[2 * HTT + j];
    bNh[js] = bhh[2 * HTT + j];
  }
  float hreg[2][4][2];
  #pragma unroll
  for (int mt = 0; mt < 2; mt++)
    #pragma unroll
    for (int r = 0; r < 4; r++) { hreg[mt][r][0] = 0.f; hreg[mt][r][1] = 0.f; }

  __syncthreads();

  for (int t = 0; t < TS; t++) {
    f32x4 acc[8][2];
    #pragma unroll
    for (int a = 0; a < 8; a++) {
      acc[a][0] = (f32x4){0.f, 0.f, 0.f, 0.f};
      acc[a][1] = (f32x4){0.f, 0.f, 0.f, 0.f};
    }

    // issue Ht[t] A-fragment loads NOW; consumed after the gh phase
    const _Float16* AH = HtHi_all + (size_t)t * NN * HG;
    const _Float16* AL = HtLo_all + (size_t)t * NN * HG;
    f16x8 gah[2][2], gal[2][2];    // [kk][mt]
    #pragma unroll
    for (int kk = 0; kk < 2; kk++)
      #pragma unroll
      for (int mt = 0; mt < 2; mt++) {
        size_t o = (size_t)(m0 + mt * 16 + col16) * HG + kk * 32 + quad * 8;
        gah[kk][mt] = *(const f16x8*)&AH[o];
        gal[kk][mt] = *(const f16x8*)&AL[o];
      }

    // gh first: A = h planes (LDS), B = Whh (registers) — hides global latency
    #pragma unroll
    for (int kk = 0; kk < 4; kk++) {
      f16x8 ah[2], al[2];
      #pragma unroll
      for (int mt = 0; mt < 2; mt++) {
        int o = (mt * 16 + col16) * 136 + kk * 32 + quad * 8;
        ah[mt] = *(const f16x8*)&hHiL[o];
        al[mt] = *(const f16x8*)&hLoL[o];
      }
      #pragma unroll
      for (int t6 = 0; t6 < 6; t6++) {
        int ai = (t6 < 4) ? t6 : t6 + 2;
        #pragma unroll
        for (int mt = 0; mt < 2; mt++) {
          acc[ai][mt] = __builtin_amdgcn_mfma_f32_16x16x32_f16(ah[mt], wgh[kk][t6], acc[ai][mt], 0, 0, 0);
          acc[ai][mt] = __builtin_amdgcn_mfma_f32_16x16x32_f16(al[mt], wgh[kk][t6], acc[ai][mt], 0, 0, 0);
        }
      }
    }
    // gi: A = Ht[t] (prefetched regs), B = Wih (LDS)
    #pragma unroll
    for (int kk = 0; kk < 2; kk++) {
      #pragma unroll
      for (int t6 = 0; t6 < 6; t6++) {
        f16x8 b = *(const f16x8*)&WihL[(gts[t6] * 16 + col16) * 72 + kk * 32 + quad * 8];
        #pragma unroll
        for (int mt = 0; mt < 2; mt++) {
          acc[t6][mt] = __builtin_amdgcn_mfma_f32_16x16x32_f16(gah[kk][mt], b, acc[t6][mt], 0, 0, 0);
          acc[t6][mt] = __builtin_amdgcn_mfma_f32_16x16x32_f16(gal[kk][mt], b, acc[t6][mt], 0, 0, 0);
        }
      }
    }
    __syncthreads();

    #pragma unroll
    for (int mt = 0; mt < 2; mt++) {
      #pragma unroll
      for (int r = 0; r < 4; r++) {
        int row = mt * 16 + quad * 4 + r;
        #pragma unroll
        for (int js = 0; js < 2; js++) {
          float R  = acc[0 + js][mt][r] + bR[js];
          float Z  = acc[2 + js][mt][r] + bZ[js];
          float Ni = acc[4 + js][mt][r] + bNi[js];
          float Nh = acc[6 + js][mt][r] + bNh[js];
          float rg = 1.f / (1.f + __expf(-R));
          float zg = 1.f / (1.f + __expf(-Z));
          float x = Ni + rg * Nh;
          float e = __expf(-2.f * fabsf(x));
          float th = (1.f - e) / (1.f + e);
          float nn = copysignf(th, x);
          float hn = (1.f - zg) * nn + zg * hreg[mt][r][js];
          hreg[mt][r][js] = hn;
          _Float16 hi = (_Float16)hn;
          hHiL[row * 136 + jj[js]] = hi;
          hLoL[row * 136 + jj[js]] = (_Float16)(hn - (float)hi);
        }
      }
    }
    __syncthreads();
  }

  #pragma unroll
  for (int mt = 0; mt < 2; mt++)
    #pragma unroll
    for (int r = 0; r < 4; r++)
      #pragma unroll
      for (int js = 0; js < 2; js++)
        hout[(size_t)(m0 + mt * 16 + quad * 4 + r) * HTT + jj[js]] = hreg[mt][r][js];
}

// ---------------- head ----------------
__global__ __launch_bounds__(256) void k_head(
    const float* __restrict__ h, const float* __restrict__ hw,
    const float* __restrict__ hb, float* __restrict__ out) {
  int lane = threadIdx.x & 63;
  int n = blockIdx.x * 4 + (threadIdx.x >> 6);
  if (n >= NN) return;
  float v = h[n * HTT + lane] * hw[lane] + h[n * HTT + 64 + lane] * hw[64 + lane];
  v = wave_sum64(v);
  if (lane == 0) out[n] = v + hb[0];
}

extern "C" void kernel_launch(void* const* d_in, const int* in_sizes, int n_in,
                              void* d_out, int out_size, void* d_ws, size_t ws_size,
                              hipStream_t stream) {
  const float* x_seq = (const float*)d_in[0];
  const int*   edge  = (const int*)d_in[1];
  const float* Wl0   = (const float*)d_in[2];
  const float* Wr0   = (const float*)d_in[3];
  const float* b0    = (const float*)d_in[4];
  const float* g0    = (const float*)d_in[5];
  const float* be0   = (const float*)d_in[6];
  const float* Wl1   = (const float*)d_in[7];
  const float* Wr1   = (const float*)d_in[8];
  const float* b1    = (const float*)d_in[9];
  const float* g1    = (const float*)d_in[10];
  const float* be1   = (const float*)d_in[11];
  const float* Wih   = (const float*)d_in[12];
  const float* Whh   = (const float*)d_in[13];
  const float* bih   = (const float*)d_in[14];
  const float* bhh   = (const float*)d_in[15];
  const float* headW = (const float*)d_in[16];
  const float* headb = (const float*)d_in[17];
  float* out = (float*)d_out;

  const int* srcp = edge;
  const int* dstp = edge + NE;

  char* ws = (char*)d_ws;
  size_t off = 0;
  auto alloc = [&](size_t bytes) -> void* {
    void* p = ws + off;
    off += (bytes + 255) & ~(size_t)255;
    return p;
  };
  int*   cnt     = (int*)alloc(NN * 4);
  int*   row_ptr = (int*)alloc((NN + 1) * 4);
  int*   col     = (int*)alloc(NE * 4);
  float* deg_inv = (float*)alloc(NN * 4);
  float* agg0    = (float*)alloc((size_t)NN * TS * 4);             // 1.3 MB
  _Float16* h0h  = (_Float16*)alloc((size_t)TS * NN * HG * 2);     // 41 MB
  _Float16* HtHi_all = (_Float16*)alloc((size_t)TS * NN * HG * 2); // 41 MB
  _Float16* HtLo_all = (_Float16*)alloc((size_t)TS * NN * HG * 2); // 41 MB
  float* h       = (float*)alloc((size_t)NN * HTT * 4);            // 10 MB
  _Float16* WihF = (_Float16*)alloc((size_t)NG * HG * 2);
  _Float16* WhhF = (_Float16*)alloc((size_t)NG * HTT * 2);
  _Float16* Wchi = (_Float16*)alloc((size_t)HG * 128 * 2);
  _Float16* Wclo = (_Float16*)alloc((size_t)HG * 128 * 2);
  (void)ws_size; (void)in_sizes; (void)n_in; (void)out_size;

  k_init<<<(NN + 255) / 256, 256, 0, stream>>>(cnt);
  k_hist<<<(NE + 255) / 256, 256, 0, stream>>>(dstp, cnt);
  k_scan<<<1, 1024, 0, stream>>>(cnt, row_ptr, deg_inv);
  k_fill<<<(NE + 255) / 256, 256, 0, stream>>>(srcp, dstp, cnt, col);
  k_cvt_f16<<<(NG * HG + 255) / 256, 256, 0, stream>>>(Wih, WihF, NG * HG);
  k_cvt_f16<<<(NG * HTT + 255) / 256, 256, 0, stream>>>(Whh, WhhF, NG * HTT);
  k_cvt_sagef16<<<(HG * 128 + 255) / 256, 256, 0, stream>>>(Wl1, Wr1, Wchi, Wclo);

  k_agg0<<<NN * TS / 256, 256, 0, stream>>>(x_seq, row_ptr, col, deg_inv, agg0);
  k_ln0<<<NN * TS / 4, 256, 0, stream>>>(x_seq, agg0, Wl0, Wr0, b0, g0, be0, h0h);
  k_sage_all<<<(NN / 32) * TS, 256, 0, stream>>>(h0h, row_ptr, col, deg_inv,
                                                 Wchi, Wclo, b1, g1, be1,
                                                 HtHi_all, HtLo_all);
  k_gru_all<<<NN / 32, 256, 0, stream>>>(HtHi_all, HtLo_all, WihF, WhhF,
                                         bih, bhh, h);
  k_head<<<5000, 256, 0, stream>>>(h, headW, headb, out);
}

// Round 9
// 539.936 us; speedup vs baseline: 2.6445x; 1.1345x over previous
//
#include <hip/hip_runtime.h>
#include <math.h>

#define NN 20000
#define NE 320000
#define TS 16
#define HG 64
#define HTT 128
#define NG 384   // 3*HT
#define LN_EPS 1e-5f

typedef __attribute__((ext_vector_type(8))) _Float16 f16x8;
typedef __attribute__((ext_vector_type(4))) float f32x4;

__device__ __forceinline__ float wave_sum64(float v) {
  #pragma unroll
  for (int off = 32; off > 0; off >>= 1) v += __shfl_xor(v, off, 64);
  return v;
}
__device__ __forceinline__ float quad_sum16(float v) {
  #pragma unroll
  for (int off = 1; off < 16; off <<= 1) v += __shfl_xor(v, off, 64);
  return v;
}

// ---------------- setup ----------------
__global__ void k_init(int* cnt) {
  int i = blockIdx.x * blockDim.x + threadIdx.x;
  if (i < NN) cnt[i] = 0;
}

__global__ void k_hist(const int* __restrict__ dst, int* cnt) {
  int e = blockIdx.x * blockDim.x + threadIdx.x;
  if (e < NE) atomicAdd(&cnt[dst[e]], 1);
}

__global__ void k_scan(int* cnt, int* row_ptr, float* deg_inv) {
  __shared__ int s[1024];
  int tid = threadIdx.x;
  int carry = 0;
  for (int base = 0; base < NN; base += 1024) {
    int n = base + tid;
    int v = (n < NN) ? cnt[n] : 0;
    s[tid] = v;
    __syncthreads();
    for (int off = 1; off < 1024; off <<= 1) {
      int t = (tid >= off) ? s[tid - off] : 0;
      __syncthreads();
      s[tid] += t;
      __syncthreads();
    }
    int incl = s[tid];
    if (n < NN) {
      int excl = carry + incl - v;
      row_ptr[n] = excl;
      cnt[n] = excl;
      deg_inv[n] = 1.0f / (float)((v > 1) ? v : 1);
    }
    carry += s[1023];
    __syncthreads();
  }
  if (tid == 0) row_ptr[NN] = carry;
}

__global__ void k_fill(const int* __restrict__ src, const int* __restrict__ dst,
                       int* cursor, int* col) {
  int e = blockIdx.x * blockDim.x + threadIdx.x;
  if (e < NE) {
    int p = atomicAdd(&cursor[dst[e]], 1);
    col[p] = src[e];
  }
}

__global__ void k_cvt_f16(const float* __restrict__ w, _Float16* __restrict__ o, int n) {
  int i = blockIdx.x * blockDim.x + threadIdx.x;
  if (i < n) o[i] = (_Float16)w[i];
}

// combined sage weight, transposed, split-fp16: Wc[n][k], k<64 -> Wl1[k][n], else Wr1
__global__ void k_cvt_sagef16(const float* __restrict__ Wl1, const float* __restrict__ Wr1,
                              _Float16* __restrict__ hi, _Float16* __restrict__ lo) {
  int i = blockIdx.x * blockDim.x + threadIdx.x;   // i = n*128 + k
  if (i < HG * 128) {
    int n = i >> 7, k = i & 127;
    float x = (k < HG) ? Wl1[k * HG + n] : Wr1[(k - HG) * HG + n];
    _Float16 h = (_Float16)x;
    hi[i] = h;
    lo[i] = (_Float16)(x - (float)h);
  }
}

// ---------------- layer-0 LN closed form: precompute centered*gain vectors + moments ----------------
// P layout: ug[64], vg[64], cg[64], be[64], moments[6] at P[256..261]
__global__ void k_moments(const float* __restrict__ Wl0, const float* __restrict__ Wr0,
                          const float* __restrict__ b0, const float* __restrict__ g0,
                          const float* __restrict__ be0, float* __restrict__ P) {
  int f = threadIdx.x;   // 64 threads
  float u = Wl0[f], v = Wr0[f], c = b0[f], g = g0[f];
  float um = wave_sum64(u) * (1.f / 64.f);
  float vm = wave_sum64(v) * (1.f / 64.f);
  float cm = wave_sum64(c) * (1.f / 64.f);
  float uc = u - um, vc = v - vm, cc = c - cm;
  float muu = wave_sum64(uc * uc) * (1.f / 64.f);
  float mvv = wave_sum64(vc * vc) * (1.f / 64.f);
  float mcc = wave_sum64(cc * cc) * (1.f / 64.f);
  float muv = wave_sum64(uc * vc) * (1.f / 64.f);
  float muc = wave_sum64(uc * cc) * (1.f / 64.f);
  float mvc = wave_sum64(vc * cc) * (1.f / 64.f);
  P[f] = uc * g; P[64 + f] = vc * g; P[128 + f] = cc * g; P[192 + f] = be0[f];
  if (f == 0) {
    P[256] = muu; P[257] = mvv; P[258] = mcc;
    P[259] = muv; P[260] = muc; P[261] = mvc;
  }
}

// xT[n][16] = x_seq[t][n]
__global__ void k_xt(const float* __restrict__ x_seq, float* __restrict__ xT) {
  int i = blockIdx.x * 256 + threadIdx.x;   // i = t*NN + n, coalesced read
  int t = i / NN, n = i - t * NN;
  xT[n * 16 + t] = x_seq[i];
}

// ---------------- agg0: neighbor-mean of x for ALL t via 64B xT rows ----------------
// wave per node; 4 edge-groups of 16 lanes; lane&15 = t.
__global__ __launch_bounds__(256) void k_agg0(
    const float* __restrict__ xT,
    const int* __restrict__ row_ptr, const int* __restrict__ col,
    const float* __restrict__ deg_inv,
    float* __restrict__ agg0) {   // [n][16]
  int lane = threadIdx.x & 63;
  int n = blockIdx.x * 4 + (threadIdx.x >> 6);
  int grp = lane >> 4, tl = lane & 15;
  int beg = row_ptr[n];
  int deg = row_ptr[n + 1] - beg;
  float s = 0.f;
  int iters = (deg + 3) >> 2;
  for (int it = 0; it < iters; it++) {
    int ev = it * 4 + grp;
    bool valid = ev < deg;
    int idx = valid ? ev : 0;
    int c = col[beg + idx];
    float v = xT[c * 16 + tl];
    s += valid ? v : 0.f;
  }
  s += __shfl_xor(s, 16, 64);
  s += __shfl_xor(s, 32, 64);
  if (grp == 0) agg0[n * 16 + tl] = s * deg_inv[n];
}

// ---------------- h0 rows: closed-form LN + ReLU -> fp16 [n][t][64] ----------------
// thread per (n, t, 8 feats): no reductions at all.
__global__ __launch_bounds__(256) void k_h0(
    const float* __restrict__ xT, const float* __restrict__ agg0,
    const float* __restrict__ P,
    _Float16* __restrict__ h0r) {   // [n][16][64]
  int i = blockIdx.x * 256 + threadIdx.x;   // < NN*128
  int n = i >> 7, rem = i & 127;
  int t = rem >> 3, f8 = (rem & 7) * 8;
  float a = agg0[n * 16 + t];
  float x = xT[n * 16 + t];
  float muu = P[256], mvv = P[257], mcc = P[258];
  float muv = P[259], muc = P[260], mvc = P[261];
  float var = a * a * muu + x * x * mvv + mcc
            + 2.f * (a * x * muv + a * muc + x * mvc);
  float rstd = rsqrtf(var + LN_EPS);
  f16x8 o;
  #pragma unroll
  for (int j = 0; j < 8; j++) {
    int f = f8 + j;
    float d = a * P[f] + x * P[64 + f] + P[128 + f];
    o[j] = (_Float16)fmaxf(d * rstd + P[192 + f], 0.f);
  }
  *(f16x8*)&h0r[(size_t)n * 1024 + t * 64 + f8] = o;
}

// ---------------- gather: neighbor-mean of h0 for ALL t at once ----------------
// wave per dest node. Edge = 2 KB row = two 1KB wave-loads (f16x8/lane).
// Accumulate packed fp16, even/odd edge split, fp32 combine. Output [n][16][64] fp16.
__global__ __launch_bounds__(256) void k_gather_all(
    const _Float16* __restrict__ h0r,
    const int* __restrict__ row_ptr, const int* __restrict__ col,
    const float* __restrict__ deg_inv,
    _Float16* __restrict__ aggA) {   // [n][16][64]
  int lane = threadIdx.x & 63;
  int n = blockIdx.x * 4 + (threadIdx.x >> 6);
  int beg = row_ptr[n];
  int deg = row_ptr[n + 1] - beg;
  f16x8 aE0 = {0,0,0,0,0,0,0,0}, aE1 = {0,0,0,0,0,0,0,0};
  f16x8 aO0 = {0,0,0,0,0,0,0,0}, aO1 = {0,0,0,0,0,0,0,0};
  int e = 0;
  for (; e + 4 <= deg; e += 4) {
    int c0 = col[beg + e + 0];   // wave-uniform -> scalar load
    int c1 = col[beg + e + 1];
    int c2 = col[beg + e + 2];
    int c3 = col[beg + e + 3];
    const f16x8* p0 = (const f16x8*)(h0r + (size_t)c0 * 1024);
    const f16x8* p1 = (const f16x8*)(h0r + (size_t)c1 * 1024);
    const f16x8* p2 = (const f16x8*)(h0r + (size_t)c2 * 1024);
    const f16x8* p3 = (const f16x8*)(h0r + (size_t)c3 * 1024);
    f16x8 d0a = p0[lane], d0b = p0[lane + 64];
    f16x8 d1a = p1[lane], d1b = p1[lane + 64];
    f16x8 d2a = p2[lane], d2b = p2[lane + 64];
    f16x8 d3a = p3[lane], d3b = p3[lane + 64];
    aE0 += d0a; aE1 += d0b;
    aO0 += d1a; aO1 += d1b;
    aE0 += d2a; aE1 += d2b;
    aO0 += d3a; aO1 += d3b;
  }
  for (; e < deg; e++) {
    int c = col[beg + e];
    const f16x8* p = (const f16x8*)(h0r + (size_t)c * 1024);
    if (e & 1) { aO0 += p[lane]; aO1 += p[lane + 64]; }
    else       { aE0 += p[lane]; aE1 += p[lane + 64]; }
  }
  float di = deg_inv[n];
  f16x8 o0, o1;
  #pragma unroll
  for (int j = 0; j < 8; j++) {
    o0[j] = (_Float16)(((float)aE0[j] + (float)aO0[j]) * di);
    o1[j] = (_Float16)(((float)aE1[j] + (float)aO1[j]) * di);
  }
  *(f16x8*)&aggA[(size_t)n * 1024 + lane * 8] = o0;
  *(f16x8*)&aggA[(size_t)n * 1024 + 512 + lane * 8] = o1;
}

// ---------------- SAGE-1 GEMM + LN + ReLU (no LDS) ----------------
// grid (ceil(NN/64), 16); 4 waves x 16 nodes. A = [agg | h0] single-fp16,
// B = split-fp16 weights (2 MFMAs/product). Output Ht split-fp16 [t][n][64].
__global__ __launch_bounds__(256) void k_sage_mm(
    const _Float16* __restrict__ aggA, const _Float16* __restrict__ h0r, // [n][16][64]
    const _Float16* __restrict__ Wchi, const _Float16* __restrict__ Wclo, // [64][128]
    const float* __restrict__ b1, const float* __restrict__ g1, const float* __restrict__ be1,
    _Float16* __restrict__ HtHi_all, _Float16* __restrict__ HtLo_all) {  // [t][n][64]
  int t = blockIdx.y;
  int lane = threadIdx.x & 63, wave = threadIdx.x >> 6;
  int col16 = lane & 15, quad = lane >> 4;
  int m0 = blockIdx.x * 64 + wave * 16;
  int arow = m0 + col16; if (arow >= NN) arow = NN - 1;
  size_t abase = (size_t)arow * 1024 + t * 64;

  f32x4 acc[4];
  #pragma unroll
  for (int nt = 0; nt < 4; nt++) acc[nt] = (f32x4){0.f, 0.f, 0.f, 0.f};

  // K 0..63: agg
  #pragma unroll
  for (int kk = 0; kk < HG; kk += 32) {
    f16x8 ah = *(const f16x8*)&aggA[abase + kk + quad * 8];
    #pragma unroll
    for (int nt = 0; nt < 4; nt++) {
      int nf = nt * 16 + col16;
      f16x8 bh = *(const f16x8*)&Wchi[nf * 128 + kk + quad * 8];
      f16x8 bl = *(const f16x8*)&Wclo[nf * 128 + kk + quad * 8];
      acc[nt] = __builtin_amdgcn_mfma_f32_16x16x32_f16(ah, bh, acc[nt], 0, 0, 0);
      acc[nt] = __builtin_amdgcn_mfma_f32_16x16x32_f16(ah, bl, acc[nt], 0, 0, 0);
    }
  }
  // K 64..127: root h0
  #pragma unroll
  for (int kk = 0; kk < HG; kk += 32) {
    f16x8 ah = *(const f16x8*)&h0r[abase + kk + quad * 8];
    #pragma unroll
    for (int nt = 0; nt < 4; nt++) {
      int nf = nt * 16 + col16;
      f16x8 bh = *(const f16x8*)&Wchi[nf * 128 + 64 + kk + quad * 8];
      f16x8 bl = *(const f16x8*)&Wclo[nf * 128 + 64 + kk + quad * 8];
      acc[nt] = __builtin_amdgcn_mfma_f32_16x16x32_f16(ah, bh, acc[nt], 0, 0, 0);
      acc[nt] = __builtin_amdgcn_mfma_f32_16x16x32_f16(ah, bl, acc[nt], 0, 0, 0);
    }
  }

  float bias[4], gg[4], bb[4];
  #pragma unroll
  for (int nt = 0; nt < 4; nt++) {
    int nf = nt * 16 + col16;
    bias[nt] = b1[nf]; gg[nt] = g1[nf]; bb[nt] = be1[nf];
  }
  #pragma unroll
  for (int r = 0; r < 4; r++) {
    float v[4];
    #pragma unroll
    for (int nt = 0; nt < 4; nt++) v[nt] = acc[nt][r] + bias[nt];
    float s = (v[0] + v[1]) + (v[2] + v[3]);
    float mu = quad_sum16(s) * (1.f / 64.f);
    float sq = 0.f;
    #pragma unroll
    for (int nt = 0; nt < 4; nt++) { v[nt] -= mu; sq += v[nt] * v[nt]; }
    float var = quad_sum16(sq) * (1.f / 64.f);
    float rstd = rsqrtf(var + LN_EPS);
    int m = m0 + quad * 4 + r;
    if (m < NN) {
      size_t base = ((size_t)t * NN + m) * HG;
      #pragma unroll
      for (int nt = 0; nt < 4; nt++) {
        float o = fmaxf(v[nt] * rstd * gg[nt] + bb[nt], 0.f);
        _Float16 hi = (_Float16)o;
        HtHi_all[base + nt * 16 + col16] = hi;
        HtLo_all[base + nt * 16 + col16] = (_Float16)(o - (float)hi);
      }
    }
  }
}

// ---------------- persistent GRU: all 16 steps in ONE kernel ----------------
__global__ __launch_bounds__(256, 2) void k_gru_all(
    const _Float16* __restrict__ HtHi_all, const _Float16* __restrict__ HtLo_all,
    const _Float16* __restrict__ WihF,   // 384 x 64 fp16
    const _Float16* __restrict__ WhhF,   // 384 x 128 fp16
    const float* __restrict__ bih, const float* __restrict__ bhh,
    float* __restrict__ hout) {
  __shared__ _Float16 WihL[NG * 72];
  __shared__ _Float16 hHiL[32 * 136];
  __shared__ _Float16 hLoL[32 * 136];

  int tid = threadIdx.x;
  int lane = tid & 63, wave = tid >> 6;
  int col16 = lane & 15, quad = lane >> 4;
  int m0 = blockIdx.x * 32;
  int gb = 2 * wave;

  for (int i = tid; i < NG * 64 / 8; i += 256) {
    int g = (i * 8) >> 6, k = (i * 8) & 63;
    *(f16x8*)&WihL[g * 72 + k] = *(const f16x8*)&WihF[g * 64 + k];
  }
  for (int i = tid; i < 32 * 136; i += 256) {
    hHiL[i] = (_Float16)0.f; hLoL[i] = (_Float16)0.f;
  }

  int gts[6];
  #pragma unroll
  for (int t6 = 0; t6 < 6; t6++)
    gts[t6] = (t6 < 2) ? (gb + t6) : (t6 < 4) ? (8 + gb + t6 - 2) : (16 + gb + t6 - 4);

  f16x8 wgh[4][6];
  #pragma unroll
  for (int kk = 0; kk < 4; kk++)
    #pragma unroll
    for (int t6 = 0; t6 < 6; t6++)
      wgh[kk][t6] = *(const f16x8*)&WhhF[(size_t)(gts[t6] * 16 + col16) * HTT + kk * 32 + quad * 8];

  int jj[2]; float bR[2], bZ[2], bNi[2], bNh[2];
  #pragma unroll
  for (int js = 0; js < 2; js++) {
    int j = (gb + js) * 16 + col16;
    jj[js] = j;
    bR[js]  = bih[j] + bhh[j];
    bZ[js]  = bih[HTT + j] + bhh[HTT + j];
    bNi[js] = bih[2 * HTT + j];
    bNh[js] = bhh[2 * HTT + j];
  }
  float hreg[2][4][2];
  #pragma unroll
  for (int mt = 0; mt < 2; mt++)
    #pragma unroll
    for (int r = 0; r < 4; r++) { hreg[mt][r][0] = 0.f; hreg[mt][r][1] = 0.f; }

  __syncthreads();

  for (int t = 0; t < TS; t++) {
    f32x4 acc[8][2];
    #pragma unroll
    for (int a = 0; a < 8; a++) {
      acc[a][0] = (f32x4){0.f, 0.f, 0.f, 0.f};
      acc[a][1] = (f32x4){0.f, 0.f, 0.f, 0.f};
    }

    const _Float16* AH = HtHi_all + (size_t)t * NN * HG;
    const _Float16* AL = HtLo_all + (size_t)t * NN * HG;
    f16x8 gah[2][2], gal[2][2];
    #pragma unroll
    for (int kk = 0; kk < 2; kk++)
      #pragma unroll
      for (int mt = 0; mt < 2; mt++) {
        size_t o = (size_t)(m0 + mt * 16 + col16) * HG + kk * 32 + quad * 8;
        gah[kk][mt] = *(const f16x8*)&AH[o];
        gal[kk][mt] = *(const f16x8*)&AL[o];
      }

    #pragma unroll
    for (int kk = 0; kk < 4; kk++) {
      f16x8 ah[2], al[2];
      #pragma unroll
      for (int mt = 0; mt < 2; mt++) {
        int o = (mt * 16 + col16) * 136 + kk * 32 + quad * 8;
        ah[mt] = *(const f16x8*)&hHiL[o];
        al[mt] = *(const f16x8*)&hLoL[o];
      }
      #pragma unroll
      for (int t6 = 0; t6 < 6; t6++) {
        int ai = (t6 < 4) ? t6 : t6 + 2;
        #pragma unroll
        for (int mt = 0; mt < 2; mt++) {
          acc[ai][mt] = __builtin_amdgcn_mfma_f32_16x16x32_f16(ah[mt], wgh[kk][t6], acc[ai][mt], 0, 0, 0);
          acc[ai][mt] = __builtin_amdgcn_mfma_f32_16x16x32_f16(al[mt], wgh[kk][t6], acc[ai][mt], 0, 0, 0);
        }
      }
    }
    #pragma unroll
    for (int kk = 0; kk < 2; kk++) {
      #pragma unroll
      for (int t6 = 0; t6 < 6; t6++) {
        f16x8 b = *(const f16x8*)&WihL[(gts[t6] * 16 + col16) * 72 + kk * 32 + quad * 8];
        #pragma unroll
        for (int mt = 0; mt < 2; mt++) {
          acc[t6][mt] = __builtin_amdgcn_mfma_f32_16x16x32_f16(gah[kk][mt], b, acc[t6][mt], 0, 0, 0);
          acc[t6][mt] = __builtin_amdgcn_mfma_f32_16x16x32_f16(gal[kk][mt], b, acc[t6][mt], 0, 0, 0);
        }
      }
    }
    __syncthreads();

    #pragma unroll
    for (int mt = 0; mt < 2; mt++) {
      #pragma unroll
      for (int r = 0; r < 4; r++) {
        int row = mt * 16 + quad * 4 + r;
        #pragma unroll
        for (int js = 0; js < 2; js++) {
          float R  = acc[0 + js][mt][r] + bR[js];
          float Z  = acc[2 + js][mt][r] + bZ[js];
          float Ni = acc[4 + js][mt][r] + bNi[js];
          float Nh = acc[6 + js][mt][r] + bNh[js];
          float rg = 1.f / (1.f + __expf(-R));
          float zg = 1.f / (1.f + __expf(-Z));
          float x = Ni + rg * Nh;
          float e = __expf(-2.f * fabsf(x));
          float th = (1.f - e) / (1.f + e);
          float nn = copysignf(th, x);
          float hn = (1.f - zg) * nn + zg * hreg[mt][r][js];
          hreg[mt][r][js] = hn;
          _Float16 hi = (_Float16)hn;
          hHiL[row * 136 + jj[js]] = hi;
          hLoL[row * 136 + jj[js]] = (_Float16)(hn - (float)hi);
        }
      }
    }
    __syncthreads();
  }

  #pragma unroll
  for (int mt = 0; mt < 2; mt++)
    #pragma unroll
    for (int r = 0; r < 4; r++)
      #pragma unroll
      for (int js = 0; js < 2; js++)
        hout[(size_t)(m0 + mt * 16 + quad * 4 + r) * HTT + jj[js]] = hreg[mt][r][js];
}

// ---------------- head ----------------
__global__ __launch_bounds__(256) void k_head(
    const float* __restrict__ h, const float* __restrict__ hw,
    const float* __restrict__ hb, float* __restrict__ out) {
  int lane = threadIdx.x & 63;
  int n = blockIdx.x * 4 + (threadIdx.x >> 6);
  if (n >= NN) return;
  float v = h[n * HTT + lane] * hw[lane] + h[n * HTT + 64 + lane] * hw[64 + lane];
  v = wave_sum64(v);
  if (lane == 0) out[n] = v + hb[0];
}

extern "C" void kernel_launch(void* const* d_in, const int* in_sizes, int n_in,
                              void* d_out, int out_size, void* d_ws, size_t ws_size,
                              hipStream_t stream) {
  const float* x_seq = (const float*)d_in[0];
  const int*   edge  = (const int*)d_in[1];
  const float* Wl0   = (const float*)d_in[2];
  const float* Wr0   = (const float*)d_in[3];
  const float* b0    = (const float*)d_in[4];
  const float* g0    = (const float*)d_in[5];
  const float* be0   = (const float*)d_in[6];
  const float* Wl1   = (const float*)d_in[7];
  const float* Wr1   = (const float*)d_in[8];
  const float* b1    = (const float*)d_in[9];
  const float* g1    = (const float*)d_in[10];
  const float* be1   = (const float*)d_in[11];
  const float* Wih   = (const float*)d_in[12];
  const float* Whh   = (const float*)d_in[13];
  const float* bih   = (const float*)d_in[14];
  const float* bhh   = (const float*)d_in[15];
  const float* headW = (const float*)d_in[16];
  const float* headb = (const float*)d_in[17];
  float* out = (float*)d_out;

  const int* srcp = edge;
  const int* dstp = edge + NE;

  char* ws = (char*)d_ws;
  size_t off = 0;
  auto alloc = [&](size_t bytes) -> void* {
    void* p = ws + off;
    off += (bytes + 255) & ~(size_t)255;
    return p;
  };
  int*   cnt     = (int*)alloc(NN * 4);
  int*   row_ptr = (int*)alloc((NN + 1) * 4);
  int*   col     = (int*)alloc(NE * 4);
  float* deg_inv = (float*)alloc(NN * 4);
  float* xT      = (float*)alloc((size_t)NN * TS * 4);             // 1.3 MB
  float* agg0    = (float*)alloc((size_t)NN * TS * 4);             // 1.3 MB
  float* P       = (float*)alloc(512 * 4);
  _Float16* h0r  = (_Float16*)alloc((size_t)NN * 1024 * 2);        // 41 MB [n][16][64]
  _Float16* aggA = (_Float16*)alloc((size_t)NN * 1024 * 2);        // 41 MB [n][16][64]
  _Float16* HtHi_all = (_Float16*)alloc((size_t)TS * NN * HG * 2); // 41 MB [t][n][64]
  _Float16* HtLo_all = (_Float16*)alloc((size_t)TS * NN * HG * 2); // 41 MB
  float* h       = (float*)alloc((size_t)NN * HTT * 4);            // 10 MB
  _Float16* WihF = (_Float16*)alloc((size_t)NG * HG * 2);
  _Float16* WhhF = (_Float16*)alloc((size_t)NG * HTT * 2);
  _Float16* Wchi = (_Float16*)alloc((size_t)HG * 128 * 2);
  _Float16* Wclo = (_Float16*)alloc((size_t)HG * 128 * 2);
  (void)ws_size; (void)in_sizes; (void)n_in; (void)out_size;

  k_init<<<(NN + 255) / 256, 256, 0, stream>>>(cnt);
  k_hist<<<(NE + 255) / 256, 256, 0, stream>>>(dstp, cnt);
  k_scan<<<1, 1024, 0, stream>>>(cnt, row_ptr, deg_inv);
  k_fill<<<(NE + 255) / 256, 256, 0, stream>>>(srcp, dstp, cnt, col);
  k_cvt_f16<<<(NG * HG + 255) / 256, 256, 0, stream>>>(Wih, WihF, NG * HG);
  k_cvt_f16<<<(NG * HTT + 255) / 256, 256, 0, stream>>>(Whh, WhhF, NG * HTT);
  k_cvt_sagef16<<<(HG * 128 + 255) / 256, 256, 0, stream>>>(Wl1, Wr1, Wchi, Wclo);
  k_moments<<<1, 64, 0, stream>>>(Wl0, Wr0, b0, g0, be0, P);

  k_xt<<<NN * TS / 256, 256, 0, stream>>>(x_seq, xT);
  k_agg0<<<NN / 4, 256, 0, stream>>>(xT, row_ptr, col, deg_inv, agg0);
  k_h0<<<NN * 128 / 256, 256, 0, stream>>>(xT, agg0, P, h0r);
  k_gather_all<<<NN / 4, 256, 0, stream>>>(h0r, row_ptr, col, deg_inv, aggA);
  k_sage_mm<<<dim3((NN + 63) / 64, TS), 256, 0, stream>>>(aggA, h0r, Wchi, Wclo,
                                                          b1, g1, be1, HtHi_all, HtLo_all);
  k_gru_all<<<NN / 32, 256, 0, stream>>>(HtHi_all, HtLo_all, WihF, WhhF,
                                         bih, bhh, h);
  k_head<<<5000, 256, 0, stream>>>(h, headW, headb, out);
}

// Round 10
// 515.601 us; speedup vs baseline: 2.7693x; 1.0472x over previous
//
#include <hip/hip_runtime.h>
#include <math.h>

#define NN 20000
#define NE 320000
#define TS 16
#define HG 64
#define HTT 128
#define NG 384   // 3*HT
#define LN_EPS 1e-5f

typedef __attribute__((ext_vector_type(8))) _Float16 f16x8;
typedef __attribute__((ext_vector_type(4))) float f32x4;

__device__ __forceinline__ float wave_sum64(float v) {
  #pragma unroll
  for (int off = 32; off > 0; off >>= 1) v += __shfl_xor(v, off, 64);
  return v;
}
__device__ __forceinline__ float quad_sum16(float v) {
  #pragma unroll
  for (int off = 1; off < 16; off <<= 1) v += __shfl_xor(v, off, 64);
  return v;
}

// ---------------- setup ----------------
__global__ void k_init(int* cnt) {
  int i = blockIdx.x * blockDim.x + threadIdx.x;
  if (i < NN) cnt[i] = 0;
}

__global__ void k_hist(const int* __restrict__ dst, int* cnt) {
  int e = blockIdx.x * blockDim.x + threadIdx.x;
  if (e < NE) atomicAdd(&cnt[dst[e]], 1);
}

__global__ void k_scan(int* cnt, int* row_ptr, float* deg_inv) {
  __shared__ int s[1024];
  int tid = threadIdx.x;
  int carry = 0;
  for (int base = 0; base < NN; base += 1024) {
    int n = base + tid;
    int v = (n < NN) ? cnt[n] : 0;
    s[tid] = v;
    __syncthreads();
    for (int off = 1; off < 1024; off <<= 1) {
      int t = (tid >= off) ? s[tid - off] : 0;
      __syncthreads();
      s[tid] += t;
      __syncthreads();
    }
    int incl = s[tid];
    if (n < NN) {
      int excl = carry + incl - v;
      row_ptr[n] = excl;
      cnt[n] = excl;
      deg_inv[n] = 1.0f / (float)((v > 1) ? v : 1);
    }
    carry += s[1023];
    __syncthreads();
  }
  if (tid == 0) row_ptr[NN] = carry;
}

__global__ void k_fill(const int* __restrict__ src, const int* __restrict__ dst,
                       int* cursor, int* col) {
  int e = blockIdx.x * blockDim.x + threadIdx.x;
  if (e < NE) {
    int p = atomicAdd(&cursor[dst[e]], 1);
    col[p] = src[e];
  }
}

__global__ void k_cvt_f16(const float* __restrict__ w, _Float16* __restrict__ o, int n) {
  int i = blockIdx.x * blockDim.x + threadIdx.x;
  if (i < n) o[i] = (_Float16)w[i];
}

// combined sage weight, transposed, split-fp16: Wc[n][k], k<64 -> Wl1[k][n], else Wr1
__global__ void k_cvt_sagef16(const float* __restrict__ Wl1, const float* __restrict__ Wr1,
                              _Float16* __restrict__ hi, _Float16* __restrict__ lo) {
  int i = blockIdx.x * blockDim.x + threadIdx.x;   // i = n*128 + k
  if (i < HG * 128) {
    int n = i >> 7, k = i & 127;
    float x = (k < HG) ? Wl1[k * HG + n] : Wr1[(k - HG) * HG + n];
    _Float16 h = (_Float16)x;
    hi[i] = h;
    lo[i] = (_Float16)(x - (float)h);
  }
}

// ---------------- layer-0 LN closed form: centered*gain vectors + moments ----------------
__global__ void k_moments(const float* __restrict__ Wl0, const float* __restrict__ Wr0,
                          const float* __restrict__ b0, const float* __restrict__ g0,
                          const float* __restrict__ be0, float* __restrict__ P) {
  int f = threadIdx.x;   // 64 threads
  float u = Wl0[f], v = Wr0[f], c = b0[f], g = g0[f];
  float um = wave_sum64(u) * (1.f / 64.f);
  float vm = wave_sum64(v) * (1.f / 64.f);
  float cm = wave_sum64(c) * (1.f / 64.f);
  float uc = u - um, vc = v - vm, cc = c - cm;
  float muu = wave_sum64(uc * uc) * (1.f / 64.f);
  float mvv = wave_sum64(vc * vc) * (1.f / 64.f);
  float mcc = wave_sum64(cc * cc) * (1.f / 64.f);
  float muv = wave_sum64(uc * vc) * (1.f / 64.f);
  float muc = wave_sum64(uc * cc) * (1.f / 64.f);
  float mvc = wave_sum64(vc * cc) * (1.f / 64.f);
  P[f] = uc * g; P[64 + f] = vc * g; P[128 + f] = cc * g; P[192 + f] = be0[f];
  if (f == 0) {
    P[256] = muu; P[257] = mvv; P[258] = mcc;
    P[259] = muv; P[260] = muc; P[261] = mvc;
  }
}

// xT[n][16] = x_seq[t][n]
__global__ void k_xt(const float* __restrict__ x_seq, float* __restrict__ xT) {
  int i = blockIdx.x * 256 + threadIdx.x;
  int t = i / NN, n = i - t * NN;
  xT[n * 16 + t] = x_seq[i];
}

// ---------------- agg0: neighbor-mean of x for ALL t ----------------
__global__ __launch_bounds__(256) void k_agg0(
    const float* __restrict__ xT,
    const int* __restrict__ row_ptr, const int* __restrict__ col,
    const float* __restrict__ deg_inv,
    float* __restrict__ agg0) {   // [n][16]
  int lane = threadIdx.x & 63;
  int n = blockIdx.x * 4 + (threadIdx.x >> 6);
  int grp = lane >> 4, tl = lane & 15;
  int beg = row_ptr[n];
  int deg = row_ptr[n + 1] - beg;
  float s = 0.f;
  int iters = (deg + 3) >> 2;
  for (int it = 0; it < iters; it++) {
    int ev = it * 4 + grp;
    bool valid = ev < deg;
    int idx = valid ? ev : 0;
    int c = col[beg + idx];
    float v = xT[c * 16 + tl];
    s += valid ? v : 0.f;
  }
  s += __shfl_xor(s, 16, 64);
  s += __shfl_xor(s, 32, 64);
  if (grp == 0) agg0[n * 16 + tl] = s * deg_inv[n];
}

// ---------------- h0 rows: closed-form LN + ReLU -> fp16 [n][t][64] ----------------
__global__ __launch_bounds__(256) void k_h0(
    const float* __restrict__ xT, const float* __restrict__ agg0,
    const float* __restrict__ P,
    _Float16* __restrict__ h0r) {   // [n][16][64]
  int i = blockIdx.x * 256 + threadIdx.x;   // < NN*128
  int n = i >> 7, rem = i & 127;
  int t = rem >> 3, f8 = (rem & 7) * 8;
  float a = agg0[n * 16 + t];
  float x = xT[n * 16 + t];
  float muu = P[256], mvv = P[257], mcc = P[258];
  float muv = P[259], muc = P[260], mvc = P[261];
  float var = a * a * muu + x * x * mvv + mcc
            + 2.f * (a * x * muv + a * muc + x * mvc);
  float rstd = rsqrtf(var + LN_EPS);
  f16x8 o;
  #pragma unroll
  for (int j = 0; j < 8; j++) {
    int f = f8 + j;
    float d = a * P[f] + x * P[64 + f] + P[128 + f];
    o[j] = (_Float16)fmaxf(d * rstd + P[192 + f], 0.f);
  }
  *(f16x8*)&h0r[(size_t)n * 1024 + t * 64 + f8] = o;
}

// ---------------- gather: neighbor-mean of h0 for ALL t at once ----------------
__global__ __launch_bounds__(256) void k_gather_all(
    const _Float16* __restrict__ h0r,
    const int* __restrict__ row_ptr, const int* __restrict__ col,
    const float* __restrict__ deg_inv,
    _Float16* __restrict__ aggA) {   // [n][16][64]
  int lane = threadIdx.x & 63;
  int n = blockIdx.x * 4 + (threadIdx.x >> 6);
  int beg = row_ptr[n];
  int deg = row_ptr[n + 1] - beg;
  f16x8 aE0 = {0,0,0,0,0,0,0,0}, aE1 = {0,0,0,0,0,0,0,0};
  f16x8 aO0 = {0,0,0,0,0,0,0,0}, aO1 = {0,0,0,0,0,0,0,0};
  int e = 0;
  for (; e + 4 <= deg; e += 4) {
    int c0 = col[beg + e + 0];
    int c1 = col[beg + e + 1];
    int c2 = col[beg + e + 2];
    int c3 = col[beg + e + 3];
    const f16x8* p0 = (const f16x8*)(h0r + (size_t)c0 * 1024);
    const f16x8* p1 = (const f16x8*)(h0r + (size_t)c1 * 1024);
    const f16x8* p2 = (const f16x8*)(h0r + (size_t)c2 * 1024);
    const f16x8* p3 = (const f16x8*)(h0r + (size_t)c3 * 1024);
    f16x8 d0a = p0[lane], d0b = p0[lane + 64];
    f16x8 d1a = p1[lane], d1b = p1[lane + 64];
    f16x8 d2a = p2[lane], d2b = p2[lane + 64];
    f16x8 d3a = p3[lane], d3b = p3[lane + 64];
    aE0 += d0a; aE1 += d0b;
    aO0 += d1a; aO1 += d1b;
    aE0 += d2a; aE1 += d2b;
    aO0 += d3a; aO1 += d3b;
  }
  for (; e < deg; e++) {
    int c = col[beg + e];
    const f16x8* p = (const f16x8*)(h0r + (size_t)c * 1024);
    if (e & 1) { aO0 += p[lane]; aO1 += p[lane + 64]; }
    else       { aE0 += p[lane]; aE1 += p[lane + 64]; }
  }
  float di = deg_inv[n];
  f16x8 o0, o1;
  #pragma unroll
  for (int j = 0; j < 8; j++) {
    o0[j] = (_Float16)(((float)aE0[j] + (float)aO0[j]) * di);
    o1[j] = (_Float16)(((float)aE1[j] + (float)aO1[j]) * di);
  }
  *(f16x8*)&aggA[(size_t)n * 1024 + lane * 8] = o0;
  *(f16x8*)&aggA[(size_t)n * 1024 + 512 + lane * 8] = o1;
}

// ---------------- SAGE-1 GEMM + LN + ReLU (no LDS); single-fp16 Ht out ----------------
__global__ __launch_bounds__(256) void k_sage_mm(
    const _Float16* __restrict__ aggA, const _Float16* __restrict__ h0r, // [n][16][64]
    const _Float16* __restrict__ Wchi, const _Float16* __restrict__ Wclo, // [64][128]
    const float* __restrict__ b1, const float* __restrict__ g1, const float* __restrict__ be1,
    _Float16* __restrict__ Ht_all) {  // [t][n][64]
  int t = blockIdx.y;
  int lane = threadIdx.x & 63, wave = threadIdx.x >> 6;
  int col16 = lane & 15, quad = lane >> 4;
  int m0 = blockIdx.x * 64 + wave * 16;
  int arow = m0 + col16; if (arow >= NN) arow = NN - 1;
  size_t abase = (size_t)arow * 1024 + t * 64;

  f32x4 acc[4];
  #pragma unroll
  for (int nt = 0; nt < 4; nt++) acc[nt] = (f32x4){0.f, 0.f, 0.f, 0.f};

  #pragma unroll
  for (int kk = 0; kk < HG; kk += 32) {
    f16x8 ah = *(const f16x8*)&aggA[abase + kk + quad * 8];
    #pragma unroll
    for (int nt = 0; nt < 4; nt++) {
      int nf = nt * 16 + col16;
      f16x8 bh = *(const f16x8*)&Wchi[nf * 128 + kk + quad * 8];
      f16x8 bl = *(const f16x8*)&Wclo[nf * 128 + kk + quad * 8];
      acc[nt] = __builtin_amdgcn_mfma_f32_16x16x32_f16(ah, bh, acc[nt], 0, 0, 0);
      acc[nt] = __builtin_amdgcn_mfma_f32_16x16x32_f16(ah, bl, acc[nt], 0, 0, 0);
    }
  }
  #pragma unroll
  for (int kk = 0; kk < HG; kk += 32) {
    f16x8 ah = *(const f16x8*)&h0r[abase + kk + quad * 8];
    #pragma unroll
    for (int nt = 0; nt < 4; nt++) {
      int nf = nt * 16 + col16;
      f16x8 bh = *(const f16x8*)&Wchi[nf * 128 + 64 + kk + quad * 8];
      f16x8 bl = *(const f16x8*)&Wclo[nf * 128 + 64 + kk + quad * 8];
      acc[nt] = __builtin_amdgcn_mfma_f32_16x16x32_f16(ah, bh, acc[nt], 0, 0, 0);
      acc[nt] = __builtin_amdgcn_mfma_f32_16x16x32_f16(ah, bl, acc[nt], 0, 0, 0);
    }
  }

  float bias[4], gg[4], bb[4];
  #pragma unroll
  for (int nt = 0; nt < 4; nt++) {
    int nf = nt * 16 + col16;
    bias[nt] = b1[nf]; gg[nt] = g1[nf]; bb[nt] = be1[nf];
  }
  #pragma unroll
  for (int r = 0; r < 4; r++) {
    float v[4];
    #pragma unroll
    for (int nt = 0; nt < 4; nt++) v[nt] = acc[nt][r] + bias[nt];
    float s = (v[0] + v[1]) + (v[2] + v[3]);
    float mu = quad_sum16(s) * (1.f / 64.f);
    float sq = 0.f;
    #pragma unroll
    for (int nt = 0; nt < 4; nt++) { v[nt] -= mu; sq += v[nt] * v[nt]; }
    float var = quad_sum16(sq) * (1.f / 64.f);
    float rstd = rsqrtf(var + LN_EPS);
    int m = m0 + quad * 4 + r;
    if (m < NN) {
      size_t base = ((size_t)t * NN + m) * HG;
      #pragma unroll
      for (int nt = 0; nt < 4; nt++) {
        float o = fmaxf(v[nt] * rstd * gg[nt] + bb[nt], 0.f);
        Ht_all[base + nt * 16 + col16] = (_Float16)o;
      }
    }
  }
}

// ---------------- persistent GRU: 16 steps, single-fp16 A, swizzled LDS, fused head ----------------
// Wih LDS: chunk (g, k8) at [g*64 + ((k8+g)&7)*8]  (48 KB, 2-way max aliasing)
// h LDS (double-buffered): chunk (row, k8) at [row*128 + ((k8+row)&15)*8]
__global__ __launch_bounds__(256, 2) void k_gru_all(
    const _Float16* __restrict__ Ht_all,   // [t][n][64]
    const _Float16* __restrict__ WihF,     // 384 x 64 fp16
    const _Float16* __restrict__ WhhF,     // 384 x 128 fp16
    const float* __restrict__ bih, const float* __restrict__ bhh,
    const float* __restrict__ headW, const float* __restrict__ headb,
    float* __restrict__ out) {
  __shared__ _Float16 WihL[NG * 64];       // 48 KB swizzled
  __shared__ _Float16 hL[2][32 * 128];     // 2 x 8 KB swizzled
  __shared__ float yL[4][32];

  int tid = threadIdx.x;
  int lane = tid & 63, wave = tid >> 6;
  int col16 = lane & 15, quad = lane >> 4;
  int m0 = blockIdx.x * 32;
  int gb = 2 * wave;

  // stage Wih (swizzled)
  for (int i = tid; i < NG * 8; i += 256) {
    int g = i >> 3, k8 = i & 7;
    *(f16x8*)&WihL[g * 64 + ((k8 + g) & 7) * 8] = *(const f16x8*)&WihF[g * 64 + k8 * 8];
  }
  for (int i = tid; i < 2 * 32 * 128; i += 256) hL[0][i] = (_Float16)0.f;

  int gts[6];
  #pragma unroll
  for (int t6 = 0; t6 < 6; t6++)
    gts[t6] = (t6 < 2) ? (gb + t6) : (t6 < 4) ? (8 + gb + t6 - 2) : (16 + gb + t6 - 4);

  // Whh fragments in registers: 24 x f16x8 = 96 VGPR, reused 16x
  f16x8 wgh[4][6];
  #pragma unroll
  for (int kk = 0; kk < 4; kk++)
    #pragma unroll
    for (int t6 = 0; t6 < 6; t6++)
      wgh[kk][t6] = *(const f16x8*)&WhhF[(size_t)(gts[t6] * 16 + col16) * HTT + kk * 32 + quad * 8];

  int jj[2]; float bR[2], bZ[2], bNi[2], bNh[2], hw[2];
  #pragma unroll
  for (int js = 0; js < 2; js++) {
    int j = (gb + js) * 16 + col16;
    jj[js] = j;
    bR[js]  = bih[j] + bhh[j];
    bZ[js]  = bih[HTT + j] + bhh[HTT + j];
    bNi[js] = bih[2 * HTT + j];
    bNh[js] = bhh[2 * HTT + j];
    hw[js]  = headW[j];
  }
  float hreg[2][4][2];
  #pragma unroll
  for (int mt = 0; mt < 2; mt++)
    #pragma unroll
    for (int r = 0; r < 4; r++) { hreg[mt][r][0] = 0.f; hreg[mt][r][1] = 0.f; }

  __syncthreads();

  for (int t = 0; t < TS; t++) {
    const _Float16* hcur = hL[t & 1];
    _Float16* hnxt = hL[(t + 1) & 1];

    f32x4 acc[8][2];
    #pragma unroll
    for (int a = 0; a < 8; a++) {
      acc[a][0] = (f32x4){0.f, 0.f, 0.f, 0.f};
      acc[a][1] = (f32x4){0.f, 0.f, 0.f, 0.f};
    }

    // prefetch Ht[t] A-fragments (global), consumed after gh phase
    const _Float16* AH = Ht_all + (size_t)t * NN * HG;
    f16x8 gah[2][2];
    #pragma unroll
    for (int kk = 0; kk < 2; kk++)
      #pragma unroll
      for (int mt = 0; mt < 2; mt++) {
        size_t o = (size_t)(m0 + mt * 16 + col16) * HG + kk * 32 + quad * 8;
        gah[kk][mt] = *(const f16x8*)&AH[o];
      }

    // gh: A = h plane (LDS, swizzled), B = Whh (registers)
    #pragma unroll
    for (int kk = 0; kk < 4; kk++) {
      f16x8 ah[2];
      #pragma unroll
      for (int mt = 0; mt < 2; mt++) {
        int row = mt * 16 + col16;
        int k8 = kk * 4 + quad;
        ah[mt] = *(const f16x8*)&hcur[row * 128 + ((k8 + row) & 15) * 8];
      }
      #pragma unroll
      for (int t6 = 0; t6 < 6; t6++) {
        int ai = (t6 < 4) ? t6 : t6 + 2;
        #pragma unroll
        for (int mt = 0; mt < 2; mt++)
          acc[ai][mt] = __builtin_amdgcn_mfma_f32_16x16x32_f16(ah[mt], wgh[kk][t6], acc[ai][mt], 0, 0, 0);
      }
    }
    // gi: A = Ht[t] (prefetched), B = Wih (LDS, swizzled)
    #pragma unroll
    for (int kk = 0; kk < 2; kk++) {
      #pragma unroll
      for (int t6 = 0; t6 < 6; t6++) {
        int g = gts[t6] * 16 + col16;
        int k8 = kk * 4 + quad;
        f16x8 b = *(const f16x8*)&WihL[g * 64 + ((k8 + g) & 7) * 8];
        #pragma unroll
        for (int mt = 0; mt < 2; mt++)
          acc[t6][mt] = __builtin_amdgcn_mfma_f32_16x16x32_f16(gah[kk][mt], b, acc[t6][mt], 0, 0, 0);
      }
    }

    // gates in registers; write new h plane (other buffer)
    #pragma unroll
    for (int mt = 0; mt < 2; mt++) {
      #pragma unroll
      for (int r = 0; r < 4; r++) {
        int row = mt * 16 + quad * 4 + r;
        #pragma unroll
        for (int js = 0; js < 2; js++) {
          float R  = acc[0 + js][mt][r] + bR[js];
          float Z  = acc[2 + js][mt][r] + bZ[js];
          float Ni = acc[4 + js][mt][r] + bNi[js];
          float Nh = acc[6 + js][mt][r] + bNh[js];
          float rg = 1.f / (1.f + __expf(-R));
          float zg = 1.f / (1.f + __expf(-Z));
          float x = Ni + rg * Nh;
          float e = __expf(-2.f * fabsf(x));
          float th = (1.f - e) / (1.f + e);
          float nn = copysignf(th, x);
          float hn = nn + zg * (hreg[mt][r][js] - nn);
          hreg[mt][r][js] = hn;
          int j = jj[js], j8 = j >> 3;
          hnxt[row * 128 + ((j8 + row) & 15) * 8 + (j & 7)] = (_Float16)hn;
        }
      }
    }
    __syncthreads();   // writes visible; all reads of hcur were drained before barrier
  }

  // fused head: y[n] = sum_j h[n][j] * w[j] + b
  #pragma unroll
  for (int mt = 0; mt < 2; mt++) {
    #pragma unroll
    for (int r = 0; r < 4; r++) {
      float py = hreg[mt][r][0] * hw[0] + hreg[mt][r][1] * hw[1];
      py = quad_sum16(py);
      if (col16 == 0) yL[wave][mt * 16 + quad * 4 + r] = py;
    }
  }
  __syncthreads();
  if (tid < 32)
    out[m0 + tid] = yL[0][tid] + yL[1][tid] + yL[2][tid] + yL[3][tid] + headb[0];
}

extern "C" void kernel_launch(void* const* d_in, const int* in_sizes, int n_in,
                              void* d_out, int out_size, void* d_ws, size_t ws_size,
                              hipStream_t stream) {
  const float* x_seq = (const float*)d_in[0];
  const int*   edge  = (const int*)d_in[1];
  const float* Wl0   = (const float*)d_in[2];
  const float* Wr0   = (const float*)d_in[3];
  const float* b0    = (const float*)d_in[4];
  const float* g0    = (const float*)d_in[5];
  const float* be0   = (const float*)d_in[6];
  const float* Wl1   = (const float*)d_in[7];
  const float* Wr1   = (const float*)d_in[8];
  const float* b1    = (const float*)d_in[9];
  const float* g1    = (const float*)d_in[10];
  const float* be1   = (const float*)d_in[11];
  const float* Wih   = (const float*)d_in[12];
  const float* Whh   = (const float*)d_in[13];
  const float* bih   = (const float*)d_in[14];
  const float* bhh   = (const float*)d_in[15];
  const float* headW = (const float*)d_in[16];
  const float* headb = (const float*)d_in[17];
  float* out = (float*)d_out;

  const int* srcp = edge;
  const int* dstp = edge + NE;

  char* ws = (char*)d_ws;
  size_t off = 0;
  auto alloc = [&](size_t bytes) -> void* {
    void* p = ws + off;
    off += (bytes + 255) & ~(size_t)255;
    return p;
  };
  int*   cnt     = (int*)alloc(NN * 4);
  int*   row_ptr = (int*)alloc((NN + 1) * 4);
  int*   col     = (int*)alloc(NE * 4);
  float* deg_inv = (float*)alloc(NN * 4);
  float* xT      = (float*)alloc((size_t)NN * TS * 4);
  float* agg0    = (float*)alloc((size_t)NN * TS * 4);
  float* P       = (float*)alloc(512 * 4);
  _Float16* h0r  = (_Float16*)alloc((size_t)NN * 1024 * 2);        // 41 MB [n][16][64]
  _Float16* aggA = (_Float16*)alloc((size_t)NN * 1024 * 2);        // 41 MB
  _Float16* Ht_all = (_Float16*)alloc((size_t)TS * NN * HG * 2);   // 41 MB [t][n][64]
  _Float16* WihF = (_Float16*)alloc((size_t)NG * HG * 2);
  _Float16* WhhF = (_Float16*)alloc((size_t)NG * HTT * 2);
  _Float16* Wchi = (_Float16*)alloc((size_t)HG * 128 * 2);
  _Float16* Wclo = (_Float16*)alloc((size_t)HG * 128 * 2);
  (void)ws_size; (void)in_sizes; (void)n_in; (void)out_size;

  k_init<<<(NN + 255) / 256, 256, 0, stream>>>(cnt);
  k_hist<<<(NE + 255) / 256, 256, 0, stream>>>(dstp, cnt);
  k_scan<<<1, 1024, 0, stream>>>(cnt, row_ptr, deg_inv);
  k_fill<<<(NE + 255) / 256, 256, 0, stream>>>(srcp, dstp, cnt, col);
  k_cvt_f16<<<(NG * HG + 255) / 256, 256, 0, stream>>>(Wih, WihF, NG * HG);
  k_cvt_f16<<<(NG * HTT + 255) / 256, 256, 0, stream>>>(Whh, WhhF, NG * HTT);
  k_cvt_sagef16<<<(HG * 128 + 255) / 256, 256, 0, stream>>>(Wl1, Wr1, Wchi, Wclo);
  k_moments<<<1, 64, 0, stream>>>(Wl0, Wr0, b0, g0, be0, P);

  k_xt<<<NN * TS / 256, 256, 0, stream>>>(x_seq, xT);
  k_agg0<<<NN / 4, 256, 0, stream>>>(xT, row_ptr, col, deg_inv, agg0);
  k_h0<<<NN * 128 / 256, 256, 0, stream>>>(xT, agg0, P, h0r);
  k_gather_all<<<NN / 4, 256, 0, stream>>>(h0r, row_ptr, col, deg_inv, aggA);
  k_sage_mm<<<dim3((NN + 63) / 64, TS), 256, 0, stream>>>(aggA, h0r, Wchi, Wclo,
                                                          b1, g1, be1, Ht_all);
  k_gru_all<<<NN / 32, 256, 0, stream>>>(Ht_all, WihF, WhhF, bih, bhh,
                                         headW, headb, out);
}